// Round 4
// baseline (9956.301 us; speedup 1.0000x reference)
//
#include <hip/hip_runtime.h>
#include <math.h>

static constexpr int B_ = 4, S_ = 2048, D_ = 1024, CH_ = 64, N_ = 32;
static constexpr float EPS_ = 1.1920929e-07f;
static constexpr float C2_  = 2.0f / 262144.0f;   // 2/(B*CH*D)
static constexpr int GRID_ = 80;                  // scan grid (<=256 CUs -> co-resident)

typedef __attribute__((ext_vector_type(8))) short bf16x8;
typedef __attribute__((ext_vector_type(4))) short bf16x4;
typedef __attribute__((ext_vector_type(4))) float f32x4;

__device__ __forceinline__ float sigf(float x)  { return 1.f/(1.f+expf(-x)); }
__device__ __forceinline__ float siluf(float x) { return x/(1.f+expf(-x)); }
__device__ __forceinline__ float silugrad(float x){
  float s = 1.f/(1.f+expf(-x));
  return s*(1.f + x*(1.f-s));
}
__device__ __forceinline__ short f2b(float f){
  union{float f;unsigned u;}c; c.f=f;
  unsigned u=c.u;
  return (short)((u + 0x7fffu + ((u>>16)&1u)) >> 16);   // RNE
}
__device__ __forceinline__ float b2f(short h){
  union{unsigned u;float f;}c; c.u=((unsigned)(unsigned short)h)<<16; return c.f;
}

// ---------------- shared GEMM core (all mode0: operands row-major [dim, K]) ----------------
// C[m,n] = sum_k A[m,k]*B[n,k]. tile 128x128, 4 waves (2x2), K-step 32,
// double-buffered LDS via global_load_lds; source-side chunk swizzle (involution
// sc = (i&3)^((i>>3)&3)) with matching read swizzle -> max 2-way bank conflict (free).
template<int WMW, int WNW, class Epi>
__device__ __forceinline__ void gemm_core(
    const short* __restrict__ A, const short* __restrict__ Bm,
    int K, int lda, int ldb, int bm0, int bn0, short* lds, Epi epi)
{
  constexpr int BMR = WMW*64, BNR = WNW*64, T = WMW*WNW*64;
  constexpr int ACH = BMR*4, BCH = BNR*4;          // 16B chunks per K-step
  constexpr int BUF = (BMR+BNR)*32;                // shorts per buffer
  const int tid = threadIdx.x, lane = tid & 63, w = tid >> 6;
  const int wm = w / WNW, wn = w % WNW, lrow = lane & 15, lk8 = lane >> 4;

  f32x4 acc[4][4];
  #pragma unroll
  for (int i=0;i<4;++i)
    #pragma unroll
    for (int j=0;j<4;++j) acc[i][j] = (f32x4){0.f,0.f,0.f,0.f};

  auto stage = [&](int buf, int k0){
    short* la = lds + buf*BUF;
    short* lb = la + BMR*32;
    #pragma unroll
    for (int i=tid; i<ACH; i+=T){
      int sc = (i&3) ^ ((i>>3)&3);
      const short* src = A + (size_t)(bm0 + (i>>2))*lda + k0 + (sc<<3);
      __builtin_amdgcn_global_load_lds(
        (const __attribute__((address_space(1))) void*)src,
        (__attribute__((address_space(3))) void*)(la + i*8), 16, 0, 0);
    }
    #pragma unroll
    for (int i=tid; i<BCH; i+=T){
      int sc = (i&3) ^ ((i>>3)&3);
      const short* src = Bm + (size_t)(bn0 + (i>>2))*ldb + k0 + (sc<<3);
      __builtin_amdgcn_global_load_lds(
        (const __attribute__((address_space(1))) void*)src,
        (__attribute__((address_space(3))) void*)(lb + i*8), 16, 0, 0);
    }
  };

  const int nk = K >> 5;
  stage(0, 0);
  int cur = 0;
  for (int ks=0; ks<nk; ++ks){
    __syncthreads();                         // drains vmcnt: stage(cur) landed
    if (ks+1 < nk) stage(cur^1, (ks+1)<<5);  // prefetch overlaps ds_read+MFMA
    short* la = lds + cur*BUF;
    short* lb = la + BMR*32;
    bf16x8 af[4], bfr[4];
    #pragma unroll
    for (int mi=0;mi<4;++mi){
      int row = wm*64 + mi*16 + lrow;
      int ch = row*4 + (lk8 ^ ((row>>1)&3));
      af[mi] = *(const bf16x8*)(la + ch*8);
    }
    #pragma unroll
    for (int ni=0;ni<4;++ni){
      int row = wn*64 + ni*16 + lrow;
      int ch = row*4 + (lk8 ^ ((row>>1)&3));
      bfr[ni] = *(const bf16x8*)(lb + ch*8);
    }
    #pragma unroll
    for (int mi=0;mi<4;++mi)
      #pragma unroll
      for (int ni=0;ni<4;++ni)
        acc[mi][ni] = __builtin_amdgcn_mfma_f32_16x16x32_bf16(af[mi], bfr[ni], acc[mi][ni], 0,0,0);
    cur ^= 1;
  }
  #pragma unroll
  for (int mi=0;mi<4;++mi)
    #pragma unroll
    for (int ni=0;ni<4;++ni)
      #pragma unroll
      for (int r=0;r<4;++r)
        epi(bm0 + wm*64 + mi*16 + lk8*4 + r, bn0 + wn*64 + ni*16 + lrow, acc[mi][ni][r]);
}

// ---------------- epilogue functors for the parallel part ----------------
struct EpiOut { float* C;
  __device__ void operator()(int r,int c,float v) const { C[(size_t)r*D_+c]=v; } };

struct EpiStoreBf { short* C;
  __device__ void operator()(int r,int c,float v) const { C[(size_t)r*D_+c]=f2b(v); } };

struct EpiBiasSig { float* C; const float* bias;
  __device__ void operator()(int r,int c,float v) const {
    C[(size_t)r*D_+c] = sigf(v + bias[c]); } };

struct EpiScat { short* dst; int part;   // -1: v[N,256,D]; 0: q rows; 1: k rows of qk[N,512,D]
  __device__ void operator()(int r,int c,float v) const {
    int b = r >> 11, s = r & 2047, t = s >> 6, ch = s & 63;
    short sv = f2b(siluf(v));
    if (part < 0) dst[((size_t)t*256 +             b*64 + ch)*D_ + c] = sv;
    else          dst[((size_t)t*512 + part*256 + b*64 + ch)*D_ + c] = sv;
  } };

template<int WMW, int WNW, class Epi>
__global__ __launch_bounds__(WMW*WNW*64)
void mgemm(const short* __restrict__ A, const short* __restrict__ Bm,
           int K, int lda, int ldb, Epi epi){
  __shared__ short lds[2*(WMW+WNW)*64*32];
  gemm_core<WMW,WNW>(A, Bm, K, lda, ldb, blockIdx.y*WMW*64, blockIdx.x*WNW*64, lds, epi);
}

// ---------------- grid barrier (device-scope; G16-correct fencing) ----------------
// ALL threads fence on both sides: release (wb dirty L2 lines cross-XCD) before
// arrive, acquire (inv per-CU L1 + stale L2 copies) after depart. Round-3 bug:
// only thread 0 fenced -> stale L1/L2 reads of data written by other blocks.
__device__ __forceinline__ void gsync(int* cnt, int* gen){
  __threadfence();                 // release: all threads' stores -> agent scope
  __syncthreads();
  if (threadIdx.x == 0){
    int g = __hip_atomic_load(gen, __ATOMIC_RELAXED, __HIP_MEMORY_SCOPE_AGENT);
    if (__hip_atomic_fetch_add(cnt, 1, __ATOMIC_ACQ_REL, __HIP_MEMORY_SCOPE_AGENT) == GRID_-1){
      __hip_atomic_store(cnt, 0, __ATOMIC_RELAXED, __HIP_MEMORY_SCOPE_AGENT);
      __hip_atomic_store(gen, g+1, __ATOMIC_RELEASE, __HIP_MEMORY_SCOPE_AGENT);
    } else {
      while (__hip_atomic_load(gen, __ATOMIC_ACQUIRE, __HIP_MEMORY_SCOPE_AGENT) == g)
        __builtin_amdgcn_s_sleep(8);
    }
  }
  __syncthreads();
  __threadfence();                 // acquire: invalidate stale L1/L2 before reads
}

// ---------------- persistent scan kernel ----------------
__global__ __launch_bounds__(256)
void scan_coop(const short* __restrict__ qk, const short* __restrict__ vbuf,
               const short* __restrict__ ktT, const float* __restrict__ gates,
               short* __restrict__ preout, float* __restrict__ hkT,
               short* __restrict__ abuf, short* __restrict__ akT,
               short* __restrict__ dpred, short* __restrict__ dpredT, short* __restrict__ dh1T,
               float* __restrict__ W0c, float* __restrict__ W1c,
               float* __restrict__ S0m, float* __restrict__ S1m,
               short* __restrict__ W0b, short* __restrict__ W1b,
               short* __restrict__ W1bT0, short* __restrict__ W1bT1,
               int* __restrict__ bar)
{
  __shared__ short lds[2*(2+2)*64*32];   // 32 KB
  const int bid = blockIdx.x;
  int* cnt = bar; int* gen = bar+1;

  for (int t=0; t<N_; ++t){
    const short* qkt = qk + (size_t)t*512*D_;
    const float al = gates[t], th = gates[N_+t], et = gates[2*N_+t];
    short* W1Tcur = (t&1) ? W1bT1 : W1bT0;
    short* W1Tnxt = (t&1) ? W1bT0 : W1bT1;

    // P1: h = [q;k] @ W0^T  (M=512,N=1024,K=1024) -> 32 tiles
    if (bid < 32){
      int bm0=(bid>>3)*128, bn0=(bid&7)*128;
      gemm_core<2,2>(qkt, W0b, 1024, 1024, 1024, bm0, bn0, lds,
        [&](int r,int c,float v){
          short sv = f2b(siluf(v));
          abuf[(size_t)r*D_+c] = sv;
          if (r>=256){ int rr=r-256;
            hkT[(size_t)c*256+rr] = v;
            akT[(size_t)c*256+rr] = sv; }
        });
    }
    gsync(cnt, gen);

    // P2: pred = a @ W1^T -> retrieve (q rows) + dpred/dpredT (k rows)
    if (bid < 32){
      int bm0=(bid>>3)*128, bn0=(bid&7)*128;
      const short* vt = vbuf + (size_t)t*256*D_;
      gemm_core<2,2>(abuf, W1b, 1024, 1024, 1024, bm0, bn0, lds,
        [&](int r,int c,float v){
          if (r < 256){ int b=r>>6, ch=r&63;
            preout[((size_t)b*S_ + t*CH_ + ch)*D_ + c] = f2b(v);
          } else { int rr=r-256;
            float dv = C2_*(v - b2f(vt[(size_t)rr*D_+c]));
            short dsv = f2b(dv);
            dpred [(size_t)rr*D_+c]  = dsv;
            dpredT[(size_t)c*256+rr] = dsv; }
        });
    }
    gsync(cnt, gen);
    if (t == N_-1) break;   // last step: retrieval only, no more updates

    // P3a: dh1T[h,r] = (sum_o W1T[h,o] dpred[r,o]) * silu'(hkT[h,r])  (16 tiles)
    // P3b: g1[o,h] = sum_r dpredT[o,r] akT[h,r]; fused W1 update       (64 tiles)
    if (bid < 16){
      int bm0=(bid>>1)*128, bn0=(bid&1)*128;
      gemm_core<2,2>(W1Tcur, dpred, 1024, 1024, 1024, bm0, bn0, lds,
        [&](int r,int c,float v){
          size_t i=(size_t)r*256+c;
          dh1T[i] = f2b(v * silugrad(hkT[i]));
        });
    } else if (bid < 80){
      int q=bid-16, bm0=(q>>3)*128, bn0=(q&7)*128;
      gemm_core<2,2>(dpredT, akT, 256, 256, 256, bm0, bn0, lds,
        [&](int r,int c,float v){
          size_t i=(size_t)r*D_+c;
          float s = et*S1m[i] - th*v;  S1m[i]=s;
          float wv = (1.f-al)*W1c[i] + s;  W1c[i]=wv;
          short b = f2b(wv);
          W1b[i] = b;
          W1Tnxt[(size_t)c*D_ + r] = b;
        });
    }
    gsync(cnt, gen);

    // P4: g0[h,i] = sum_r dh1T[h,r] ktT[i,r]; fused W0 update (64 tiles)
    if (bid < 64){
      int bm0=(bid>>3)*128, bn0=(bid&7)*128;
      gemm_core<2,2>(dh1T, ktT + (size_t)t*D_*256, 256, 256, 256, bm0, bn0, lds,
        [&](int r,int c,float v){
          size_t i=(size_t)r*D_+c;
          float s = et*S0m[i] - th*v;  S0m[i]=s;
          float wv = (1.f-al)*W0c[i] + s;  W0c[i]=wv;
          W0b[i] = f2b(wv);
        });
    }
    gsync(cnt, gen);
  }
}

// ---------------- small kernels ----------------
__device__ __forceinline__ float block_sum(float v){
  #pragma unroll
  for (int o=32;o>0;o>>=1) v += __shfl_down(v,o,64);
  __shared__ float sm4[4];
  int lane = threadIdx.x & 63, w = threadIdx.x >> 6;
  if (lane==0) sm4[w]=v;
  __syncthreads();
  float r = sm4[0]+sm4[1]+sm4[2]+sm4[3];
  __syncthreads();
  return r;
}

__global__ void conv_k(const float* __restrict__ s, short* __restrict__ d, int n4){
  int i = blockIdx.x*256 + threadIdx.x;
  if (i >= n4) return;
  float4 v = ((const float4*)s)[i];
  bf16x4 o = { f2b(v.x), f2b(v.y), f2b(v.z), f2b(v.w) };
  ((bf16x4*)d)[i] = o;
}

// bf16 [R,C] -> [C,R] tiled transpose, batched over blockIdx.z
__global__ __launch_bounds__(256)
void transpose_bf_k(const short* __restrict__ in, short* __restrict__ out,
                    int R, int C, size_t ibs, size_t obs){
  __shared__ short t[64][68];
  const short* ip = in + blockIdx.z*ibs;
  short* op = out + blockIdx.z*obs;
  int r0 = blockIdx.y*64, c0 = blockIdx.x*64;
  for (int i=threadIdx.x; i<1024; i+=256){
    int r = i>>4, c4 = (i&15)*4;
    *(bf16x4*)&t[r][c4] = *(const bf16x4*)&ip[(size_t)(r0+r)*C + c0+c4];
  }
  __syncthreads();
  for (int i=threadIdx.x; i<1024; i+=256){
    int c = i>>4, r4 = (i&15)*4;
    bf16x4 v = { t[r4+0][c], t[r4+1][c], t[r4+2][c], t[r4+3][c] };
    *(bf16x4*)&op[(size_t)(c0+c)*R + r0+r4] = v;
  }
}

// fp32 [R,C] -> bf16 [C,R]
__global__ __launch_bounds__(256)
void transpose_f2b_k(const float* __restrict__ in, short* __restrict__ out,
                     int R, int C, size_t ibs, size_t obs){
  __shared__ short t[64][68];
  const float* ip = in + blockIdx.z*ibs;
  short* op = out + blockIdx.z*obs;
  int r0 = blockIdx.y*64, c0 = blockIdx.x*64;
  for (int i=threadIdx.x; i<1024; i+=256){
    int r = i>>4, c4 = (i&15)*4;
    float4 v = *(const float4*)&ip[(size_t)(r0+r)*C + c0+c4];
    t[r][c4+0]=f2b(v.x); t[r][c4+1]=f2b(v.y); t[r][c4+2]=f2b(v.z); t[r][c4+3]=f2b(v.w);
  }
  __syncthreads();
  for (int i=threadIdx.x; i<1024; i+=256){
    int c = i>>4, r4 = (i&15)*4;
    bf16x4 v = { t[r4+0][c], t[r4+1][c], t[r4+2][c], t[r4+3][c] };
    *(bf16x4*)&op[(size_t)(c0+c)*R + r0+r4] = v;
  }
}

__global__ void chunk_mean_k(const float* __restrict__ x, short* __restrict__ cm){
  int idx = blockIdx.x*256 + threadIdx.x;     // B*N*D = 131072
  int d  = idx & (D_-1);
  int bn = idx >> 10;
  int b = bn >> 5, n = bn & 31;
  const float* p = x + ((size_t)b*S_ + n*CH_)*D_ + d;
  float s = 0.f;
  for (int ch=0; ch<CH_; ++ch) s += p[(size_t)ch*D_];
  cm[idx] = f2b(s * (1.f/CH_));
}

__global__ void gate_reduce_k(const float* __restrict__ Z, float* __restrict__ outp, float scale){
  int n = blockIdx.x;
  float s = 0.f;
  for (int b=0;b<B_;++b){
    const float* row = Z + (size_t)(b*N_+n)*D_;
    for (int j=threadIdx.x; j<D_; j+=256) s += row[j];
  }
  float tot = block_sum(s);
  if (threadIdx.x==0) outp[n] = scale * tot / (float)(B_*D_);
}

__global__ void rmsnorm2_k(const float* __restrict__ x, const float* __restrict__ gs,
                           const float* __restrict__ gr, short* __restrict__ xs, short* __restrict__ xr){
  size_t row = blockIdx.x;
  const float* xp = x + row*D_;
  float s = 0.f;
  for (int j=threadIdx.x;j<D_;j+=256){ float v=xp[j]; s+=v*v; }
  float tot = block_sum(s);
  float rinv = rsqrtf(tot/(float)D_ + EPS_);
  for (int j=threadIdx.x;j<D_;j+=256){
    float v = xp[j]*rinv;
    xs[row*D_+j] = f2b(v*gs[j]);
    xr[row*D_+j] = f2b(v*gr[j]);
  }
}

__global__ void l2norm_b(short* __restrict__ qk){
  size_t row = blockIdx.x;
  short* p = qk + row*D_;
  float s = 0.f;
  for (int j=threadIdx.x;j<D_;j+=256){ float v=b2f(p[j]); s+=v*v; }
  float tot = block_sum(s);
  float inv = 1.f / fmaxf(sqrtf(tot), 1e-12f);
  for (int j=threadIdx.x;j<D_;j+=256) p[j] = f2b(b2f(p[j])*inv);
}

__global__ void init_state_k(const float* __restrict__ W0, const float* __restrict__ W1,
                             float* __restrict__ W0c, float* __restrict__ W1c,
                             float* __restrict__ S0, float* __restrict__ S1,
                             short* __restrict__ W0b, short* __restrict__ W1b,
                             int* __restrict__ bar){
  size_t i = (size_t)blockIdx.x*256 + threadIdx.x;
  float a0=W0[i], a1=W1[i];
  W0c[i]=a0; W1c[i]=a1; S0[i]=0.f; S1[i]=0.f;
  W0b[i]=f2b(a0); W1b[i]=f2b(a1);
  if (i==0){ bar[0]=0; bar[1]=0; }
}

// ---------------- host ----------------
extern "C" void kernel_launch(void* const* d_in, const int* in_sizes, int n_in,
                              void* d_out, int out_size, void* d_ws, size_t ws_size,
                              hipStream_t stream) {
  (void)in_sizes; (void)n_in; (void)out_size;
  const float* x    = (const float*)d_in[0];
  const float* Mmet = (const float*)d_in[1];
  const float* Wk   = (const float*)d_in[2];
  const float* Wv   = (const float*)d_in[3];
  const float* Wq   = (const float*)d_in[4];
  const float* Wo   = (const float*)d_in[5];
  const float* Wgd  = (const float*)d_in[6];
  const float* bgd  = (const float*)d_in[7];
  const float* Wgl  = (const float*)d_in[8];
  const float* bgl  = (const float*)d_in[9];
  const float* Wgm  = (const float*)d_in[10];
  const float* bgm  = (const float*)d_in[11];
  const float* g_store = (const float*)d_in[12];
  const float* g_retr  = (const float*)d_in[13];
  const float* W0   = (const float*)d_in[14];
  const float* W1   = (const float*)d_in[15];
  float* out = (float*)d_out;

  if (ws_size < 166000000ull) return;   // layout below ~= 154 MB
  short* qk    = (short*)d_ws;          // [N,512,D] q rows 0..255, k rows 256..511
  short* vbuf  = qk    + 16777216;      // [N,256,D]
  short* xs    = vbuf  + 8388608;       // [B*S,D]
  short* xr    = xs    + 8388608;       // [B*S,D]  -> reused as ktT [N,1024,256]
  short* t1    = xr    + 8388608;       // [B*S,D]  -> reused as preout
  short* cm    = t1    + 8388608;       // [128,D]
  short* Wkb   = cm    + 131072;
  short* Wvb   = Wkb   + 1048576;
  short* Wqb   = Wvb   + 1048576;
  short* Wob   = Wqb   + 1048576;
  short* Wgdb  = Wob   + 1048576;
  short* Wglb  = Wgdb  + 1048576;
  short* Wgmb  = Wglb  + 1048576;
  short* MmetT = Wgmb  + 1048576;       // [B,D,D] transposed (bf16)
  short* W0b   = MmetT + 4194304;
  short* W1b   = W0b   + 1048576;
  short* W1bT0 = W1b   + 1048576;
  short* W1bT1 = W1bT0 + 1048576;
  short* abuf  = W1bT1 + 1048576;       // [512,D]
  short* akT   = abuf  + 524288;        // [D,256]
  short* dpred = akT   + 262144;        // [256,D]
  short* dpredT= dpred + 262144;        // [D,256]
  short* dh1T  = dpredT+ 262144;        // [D,256]
  float* Zg    = (float*)(dh1T + 262144);  // [128,D]
  float* gates = Zg    + 131072;        // [96]
  float* hkT   = gates + 128;           // [D,256]
  float* W0c   = hkT   + 262144;
  float* W1c   = W0c   + 1048576;
  float* S0m   = W1c   + 1048576;
  float* S1m   = S0m   + 1048576;
  int*   bar   = (int*)(S1m + 1048576);
  short* ktT   = xr;                    // alias (xr dead before ktT written)
  short* preout= t1;                    // alias (t1 dead before scan)

  // conversions / init / static transposes
  conv_k<<<1024,256,0,stream>>>(Wk,  Wkb,  262144);
  conv_k<<<1024,256,0,stream>>>(Wv,  Wvb,  262144);
  conv_k<<<1024,256,0,stream>>>(Wq,  Wqb,  262144);
  conv_k<<<1024,256,0,stream>>>(Wo,  Wob,  262144);
  conv_k<<<1024,256,0,stream>>>(Wgd, Wgdb, 262144);
  conv_k<<<1024,256,0,stream>>>(Wgl, Wglb, 262144);
  conv_k<<<1024,256,0,stream>>>(Wgm, Wgmb, 262144);
  transpose_f2b_k<<<dim3(16,16,4),256,0,stream>>>(Mmet, MmetT, 1024, 1024, 1048576, 1048576);
  init_state_k<<<4096,256,0,stream>>>(W0, W1, W0c, W1c, S0m, S1m, W0b, W1b, bar);
  transpose_bf_k<<<dim3(16,16,1),256,0,stream>>>(W1b, W1bT0, 1024, 1024, 0, 0);

  // chunk means + gates
  chunk_mean_k<<<512,256,0,stream>>>(x, cm);
  {
    dim3 g(8,1);
    mgemm<2,2,EpiBiasSig><<<g,256,0,stream>>>(cm, Wgdb, 1024,1024,1024, EpiBiasSig{Zg, bgd});
    gate_reduce_k<<<N_,256,0,stream>>>(Zg, gates + 0,    0.01f);   // MEM_DECAY
    mgemm<2,2,EpiBiasSig><<<g,256,0,stream>>>(cm, Wglb, 1024,1024,1024, EpiBiasSig{Zg, bgl});
    gate_reduce_k<<<N_,256,0,stream>>>(Zg, gates + N_,   0.1f);    // MEM_LR
    mgemm<2,2,EpiBiasSig><<<g,256,0,stream>>>(cm, Wgmb, 1024,1024,1024, EpiBiasSig{Zg, bgm});
    gate_reduce_k<<<N_,256,0,stream>>>(Zg, gates + 2*N_, 0.9f);    // MEM_MOM
  }
  // dual RMSNorm
  rmsnorm2_k<<<B_*S_,256,0,stream>>>(x, g_store, g_retr, xs, xr);
  // t1 = xs @ Mmet[b]  (B = MmetT[b] mode0)
  for (int b=0;b<B_;++b)
    mgemm<2,2,EpiStoreBf><<<dim3(8,16),256,0,stream>>>(
      xs + (size_t)b*S_*D_, MmetT + (size_t)b*D_*D_, 1024,1024,1024,
      EpiStoreBf{t1 + (size_t)b*S_*D_});
  // k, v, q projections with silu + chunk scatter
  {
    dim3 g(8,64);
    mgemm<2,2,EpiScat><<<g,256,0,stream>>>(t1, Wkb, 1024,1024,1024, EpiScat{qk, 1});
    mgemm<2,2,EpiScat><<<g,256,0,stream>>>(xs, Wvb, 1024,1024,1024, EpiScat{vbuf,-1});
    mgemm<2,2,EpiScat><<<g,256,0,stream>>>(xr, Wqb, 1024,1024,1024, EpiScat{qk, 0});
  }
  l2norm_b<<<N_*512,256,0,stream>>>(qk);
  // ktT[t][i][r] = qk[t][256+r][i]  (k rows, per chunk)
  transpose_bf_k<<<dim3(16,4,32),256,0,stream>>>(qk + 256*1024, ktT, 256, 1024,
                                                 (size_t)512*1024, (size_t)1024*256);

  // persistent scan (one launch, manual grid barriers)
  scan_coop<<<GRID_,256,0,stream>>>(qk, vbuf, ktT, gates, preout, hkT, abuf, akT,
                                    dpred, dpredT, dh1T, W0c, W1c, S0m, S1m,
                                    W0b, W1b, W1bT0, W1bT1, bar);

  // out = preout @ Wo^T
  mgemm<2,2,EpiOut><<<dim3(8,64),256,0,stream>>>(preout, Wob, 1024,1024,1024, EpiOut{out});
}

// Round 5
// 7418.235 us; speedup vs baseline: 1.3421x; 1.3421x over previous
//
#include <hip/hip_runtime.h>
#include <math.h>

static constexpr int B_ = 4, S_ = 2048, D_ = 1024, CH_ = 64, N_ = 32;
static constexpr float EPS_ = 1.1920929e-07f;
static constexpr float C2_  = 2.0f / 262144.0f;   // 2/(B*CH*D)
static constexpr int GRID_ = 80;                  // scan grid (<=256 CUs -> co-resident)
static constexpr int SC_   = 0x11;                // CPol sc0|sc1: coherence-point access (gfx94x/950)

typedef __attribute__((ext_vector_type(8))) short bf16x8;
typedef __attribute__((ext_vector_type(4))) short bf16x4;
typedef __attribute__((ext_vector_type(4))) float f32x4;

__device__ __forceinline__ float sigf(float x)  { return 1.f/(1.f+expf(-x)); }
__device__ __forceinline__ float siluf(float x) { return x/(1.f+expf(-x)); }
__device__ __forceinline__ float silugrad(float x){
  float s = 1.f/(1.f+expf(-x));
  return s*(1.f + x*(1.f-s));
}
__device__ __forceinline__ short f2b(float f){
  union{float f;unsigned u;}c; c.f=f;
  unsigned u=c.u;
  return (short)((u + 0x7fffu + ((u>>16)&1u)) >> 16);   // RNE
}
__device__ __forceinline__ float b2f(short h){
  union{unsigned u;float f;}c; c.u=((unsigned)(unsigned short)h)<<16; return c.f;
}

// coherence-point scalar access (sc0|sc1, no cache maintenance): for data shared
// across blocks within the persistent scan kernel. Bypasses stale L1/L2 copies.
__device__ __forceinline__ void st_sys(short* p, short v){
  __hip_atomic_store(p, v, __ATOMIC_RELAXED, __HIP_MEMORY_SCOPE_SYSTEM); }
__device__ __forceinline__ void st_sysf(float* p, float v){
  __hip_atomic_store(p, v, __ATOMIC_RELAXED, __HIP_MEMORY_SCOPE_SYSTEM); }
__device__ __forceinline__ float ld_sysf(const float* p){
  return __hip_atomic_load(p, __ATOMIC_RELAXED, __HIP_MEMORY_SCOPE_SYSTEM); }

// ---------------- shared GEMM core (operands row-major [dim, K]) ----------------
// C[m,n] = sum_k A[m,k]*B[n,k]. tile 128x128, 4 waves (2x2), K-step 32,
// double-buffered LDS via global_load_lds; source-side chunk swizzle (involution
// sc = (i&3)^((i>>3)&3)) with matching read swizzle -> max 2-way bank conflict (free).
// AAUX/BAUX: cache-policy bits for the staging loads (0 = cached, SC_ = bypass-coherent).
template<int WMW, int WNW, int AAUX, int BAUX, class Epi>
__device__ __forceinline__ void gemm_core(
    const short* __restrict__ A, const short* __restrict__ Bm,
    int K, int lda, int ldb, int bm0, int bn0, short* lds, Epi epi)
{
  constexpr int BMR = WMW*64, BNR = WNW*64, T = WMW*WNW*64;
  constexpr int ACH = BMR*4, BCH = BNR*4;          // 16B chunks per K-step
  constexpr int BUF = (BMR+BNR)*32;                // shorts per buffer
  const int tid = threadIdx.x, lane = tid & 63, w = tid >> 6;
  const int wm = w / WNW, wn = w % WNW, lrow = lane & 15, lk8 = lane >> 4;

  f32x4 acc[4][4];
  #pragma unroll
  for (int i=0;i<4;++i)
    #pragma unroll
    for (int j=0;j<4;++j) acc[i][j] = (f32x4){0.f,0.f,0.f,0.f};

  auto stage = [&](int buf, int k0){
    short* la = lds + buf*BUF;
    short* lb = la + BMR*32;
    #pragma unroll
    for (int i=tid; i<ACH; i+=T){
      int sc = (i&3) ^ ((i>>3)&3);
      const short* src = A + (size_t)(bm0 + (i>>2))*lda + k0 + (sc<<3);
      __builtin_amdgcn_global_load_lds(
        (const __attribute__((address_space(1))) void*)src,
        (__attribute__((address_space(3))) void*)(la + i*8), 16, 0, AAUX);
    }
    #pragma unroll
    for (int i=tid; i<BCH; i+=T){
      int sc = (i&3) ^ ((i>>3)&3);
      const short* src = Bm + (size_t)(bn0 + (i>>2))*ldb + k0 + (sc<<3);
      __builtin_amdgcn_global_load_lds(
        (const __attribute__((address_space(1))) void*)src,
        (__attribute__((address_space(3))) void*)(lb + i*8), 16, 0, BAUX);
    }
  };

  const int nk = K >> 5;
  stage(0, 0);
  int cur = 0;
  for (int ks=0; ks<nk; ++ks){
    __syncthreads();                         // drains vmcnt: stage(cur) landed
    if (ks+1 < nk) stage(cur^1, (ks+1)<<5);  // prefetch overlaps ds_read+MFMA
    short* la = lds + cur*BUF;
    short* lb = la + BMR*32;
    bf16x8 af[4], bfr[4];
    #pragma unroll
    for (int mi=0;mi<4;++mi){
      int row = wm*64 + mi*16 + lrow;
      int ch = row*4 + (lk8 ^ ((row>>1)&3));
      af[mi] = *(const bf16x8*)(la + ch*8);
    }
    #pragma unroll
    for (int ni=0;ni<4;++ni){
      int row = wn*64 + ni*16 + lrow;
      int ch = row*4 + (lk8 ^ ((row>>1)&3));
      bfr[ni] = *(const bf16x8*)(lb + ch*8);
    }
    #pragma unroll
    for (int mi=0;mi<4;++mi)
      #pragma unroll
      for (int ni=0;ni<4;++ni)
        acc[mi][ni] = __builtin_amdgcn_mfma_f32_16x16x32_bf16(af[mi], bfr[ni], acc[mi][ni], 0,0,0);
    cur ^= 1;
  }
  #pragma unroll
  for (int mi=0;mi<4;++mi)
    #pragma unroll
    for (int ni=0;ni<4;++ni)
      #pragma unroll
      for (int r=0;r<4;++r)
        epi(bm0 + wm*64 + mi*16 + lk8*4 + r, bn0 + wn*64 + ni*16 + lrow, acc[mi][ni][r]);
}

// ---------------- epilogue functors for the parallel part ----------------
struct EpiOut { float* C;
  __device__ void operator()(int r,int c,float v) const { C[(size_t)r*D_+c]=v; } };

struct EpiStoreBf { short* C;
  __device__ void operator()(int r,int c,float v) const { C[(size_t)r*D_+c]=f2b(v); } };

struct EpiBiasSig { float* C; const float* bias;
  __device__ void operator()(int r,int c,float v) const {
    C[(size_t)r*D_+c] = sigf(v + bias[c]); } };

struct EpiScat { short* dst; int part;   // -1: v[N,256,D]; 0: q rows; 1: k rows of qk[N,512,D]
  __device__ void operator()(int r,int c,float v) const {
    int b = r >> 11, s = r & 2047, t = s >> 6, ch = s & 63;
    short sv = f2b(siluf(v));
    if (part < 0) dst[((size_t)t*256 +             b*64 + ch)*D_ + c] = sv;
    else          dst[((size_t)t*512 + part*256 + b*64 + ch)*D_ + c] = sv;
  } };

template<int WMW, int WNW, class Epi>
__global__ __launch_bounds__(WMW*WNW*64)
void mgemm(const short* __restrict__ A, const short* __restrict__ Bm,
           int K, int lda, int ldb, Epi epi){
  __shared__ short lds[2*(WMW+WNW)*64*32];
  gemm_core<WMW,WNW,0,0>(A, Bm, K, lda, ldb, blockIdx.y*WMW*64, blockIdx.x*WNW*64, lds, epi);
}

// ---------------- grid barrier: relaxed monotonic counter ----------------
// No fences, no cache maintenance anywhere (round-4 lesson: per-thread wbl2 +
// acquire-spin buffer_inv thrashed every L2). Cross-block data instead moves
// via sc0|sc1 coherence-point accesses. __syncthreads before arrive drains
// each wave's vmcnt, so all sc1 stores have reached the coherence point.
__device__ __forceinline__ void gsync(int* cnt, int target){
  __syncthreads();
  if (threadIdx.x == 0){
    __hip_atomic_fetch_add(cnt, 1, __ATOMIC_RELAXED, __HIP_MEMORY_SCOPE_AGENT);
    while (__hip_atomic_load(cnt, __ATOMIC_RELAXED, __HIP_MEMORY_SCOPE_AGENT) < target)
      __builtin_amdgcn_s_sleep(4);
  }
  __syncthreads();
}

// ---------------- persistent scan kernel ----------------
// Masters (W0c,W1c,S0m,S1m): block-private (fixed tile ownership) -> plain cached.
// Shared step data (W0b,W1b,W1bT,abuf,akT,dpred,dpredT,dh1T,hkT): sc1 both sides.
__global__ __launch_bounds__(256)
void scan_coop(const short* __restrict__ qk, const short* __restrict__ vbuf,
               const short* __restrict__ ktT, const float* __restrict__ gates,
               short* __restrict__ preout, float* __restrict__ hkT,
               short* __restrict__ abuf, short* __restrict__ akT,
               short* __restrict__ dpred, short* __restrict__ dpredT, short* __restrict__ dh1T,
               float* __restrict__ W0c, float* __restrict__ W1c,
               float* __restrict__ S0m, float* __restrict__ S1m,
               short* __restrict__ W0b, short* __restrict__ W1b,
               short* __restrict__ W1bT0, short* __restrict__ W1bT1,
               int* __restrict__ bar)
{
  __shared__ short lds[2*(2+2)*64*32];   // 32 KB
  const int bid = blockIdx.x;
  int* cnt = bar;
  int ep = 0;

  for (int t=0; t<N_; ++t){
    const short* qkt = qk + (size_t)t*512*D_;
    const float al = gates[t], th = gates[N_+t], et = gates[2*N_+t];
    short* W1Tcur = (t&1) ? W1bT1 : W1bT0;
    short* W1Tnxt = (t&1) ? W1bT0 : W1bT1;

    // P1: h = [q;k] @ W0^T  (M=512,N=1024,K=1024) -> 32 tiles
    if (bid < 32){
      int bm0=(bid>>3)*128, bn0=(bid&7)*128;
      gemm_core<2,2,0,SC_>(qkt, W0b, 1024, 1024, 1024, bm0, bn0, lds,
        [&](int r,int c,float v){
          short sv = f2b(siluf(v));
          st_sys(&abuf[(size_t)r*D_+c], sv);
          if (r>=256){ int rr=r-256;
            st_sysf(&hkT[(size_t)c*256+rr], v);
            st_sys (&akT[(size_t)c*256+rr], sv); }
        });
    }
    gsync(cnt, (++ep)*GRID_);

    // P2: pred = a @ W1^T -> retrieve (q rows) + dpred/dpredT (k rows)
    if (bid < 32){
      int bm0=(bid>>3)*128, bn0=(bid&7)*128;
      const short* vt = vbuf + (size_t)t*256*D_;
      gemm_core<2,2,SC_,SC_>(abuf, W1b, 1024, 1024, 1024, bm0, bn0, lds,
        [&](int r,int c,float v){
          if (r < 256){ int b=r>>6, ch=r&63;
            preout[((size_t)b*S_ + t*CH_ + ch)*D_ + c] = f2b(v);   // read only post-scan
          } else { int rr=r-256;
            float dv = C2_*(v - b2f(vt[(size_t)rr*D_+c]));
            short dsv = f2b(dv);
            st_sys(&dpred [(size_t)rr*D_+c],  dsv);
            st_sys(&dpredT[(size_t)c*256+rr], dsv); }
        });
    }
    gsync(cnt, (++ep)*GRID_);
    if (t == N_-1) break;   // last step: retrieval only, no more updates

    // P3a: dh1T[h,r] = (sum_o W1T[h,o] dpred[r,o]) * silu'(hkT[h,r])  (16 tiles)
    // P3b: g1[o,h] = sum_r dpredT[o,r] akT[h,r]; fused W1 update       (64 tiles)
    if (bid < 16){
      int bm0=(bid>>1)*128, bn0=(bid&1)*128;
      gemm_core<2,2,SC_,SC_>(W1Tcur, dpred, 1024, 1024, 1024, bm0, bn0, lds,
        [&](int r,int c,float v){
          size_t i=(size_t)r*256+c;
          st_sys(&dh1T[i], f2b(v * silugrad(ld_sysf(&hkT[i]))));
        });
    } else if (bid < 80){
      int q=bid-16, bm0=(q>>3)*128, bn0=(q&7)*128;
      gemm_core<2,2,SC_,SC_>(dpredT, akT, 256, 256, 256, bm0, bn0, lds,
        [&](int r,int c,float v){
          size_t i=(size_t)r*D_+c;
          float s = et*S1m[i] - th*v;  S1m[i]=s;           // masters: private, cached
          float wv = (1.f-al)*W1c[i] + s;  W1c[i]=wv;
          short b = f2b(wv);
          st_sys(&W1b[i], b);
          st_sys(&W1Tnxt[(size_t)c*D_ + r], b);
        });
    }
    gsync(cnt, (++ep)*GRID_);

    // P4: g0[h,i] = sum_r dh1T[h,r] ktT[i,r]; fused W0 update (64 tiles)
    if (bid < 64){
      int bm0=(bid>>3)*128, bn0=(bid&7)*128;
      gemm_core<2,2,SC_,0>(dh1T, ktT + (size_t)t*D_*256, 256, 256, 256, bm0, bn0, lds,
        [&](int r,int c,float v){
          size_t i=(size_t)r*D_+c;
          float s = et*S0m[i] - th*v;  S0m[i]=s;
          float wv = (1.f-al)*W0c[i] + s;  W0c[i]=wv;
          st_sys(&W0b[i], f2b(wv));
        });
    }
    gsync(cnt, (++ep)*GRID_);
  }
}

// ---------------- small kernels ----------------
__device__ __forceinline__ float block_sum(float v){
  #pragma unroll
  for (int o=32;o>0;o>>=1) v += __shfl_down(v,o,64);
  __shared__ float sm4[4];
  int lane = threadIdx.x & 63, w = threadIdx.x >> 6;
  if (lane==0) sm4[w]=v;
  __syncthreads();
  float r = sm4[0]+sm4[1]+sm4[2]+sm4[3];
  __syncthreads();
  return r;
}

__global__ void conv_k(const float* __restrict__ s, short* __restrict__ d, int n4){
  int i = blockIdx.x*256 + threadIdx.x;
  if (i >= n4) return;
  float4 v = ((const float4*)s)[i];
  bf16x4 o = { f2b(v.x), f2b(v.y), f2b(v.z), f2b(v.w) };
  ((bf16x4*)d)[i] = o;
}

// bf16 [R,C] -> [C,R] tiled transpose, batched over blockIdx.z
__global__ __launch_bounds__(256)
void transpose_bf_k(const short* __restrict__ in, short* __restrict__ out,
                    int R, int C, size_t ibs, size_t obs){
  __shared__ short t[64][68];
  const short* ip = in + blockIdx.z*ibs;
  short* op = out + blockIdx.z*obs;
  int r0 = blockIdx.y*64, c0 = blockIdx.x*64;
  for (int i=threadIdx.x; i<1024; i+=256){
    int r = i>>4, c4 = (i&15)*4;
    *(bf16x4*)&t[r][c4] = *(const bf16x4*)&ip[(size_t)(r0+r)*C + c0+c4];
  }
  __syncthreads();
  for (int i=threadIdx.x; i<1024; i+=256){
    int c = i>>4, r4 = (i&15)*4;
    bf16x4 v = { t[r4+0][c], t[r4+1][c], t[r4+2][c], t[r4+3][c] };
    *(bf16x4*)&op[(size_t)(c0+c)*R + r0+r4] = v;
  }
}

// fp32 [R,C] -> bf16 [C,R]
__global__ __launch_bounds__(256)
void transpose_f2b_k(const float* __restrict__ in, short* __restrict__ out,
                     int R, int C, size_t ibs, size_t obs){
  __shared__ short t[64][68];
  const float* ip = in + blockIdx.z*ibs;
  short* op = out + blockIdx.z*obs;
  int r0 = blockIdx.y*64, c0 = blockIdx.x*64;
  for (int i=threadIdx.x; i<1024; i+=256){
    int r = i>>4, c4 = (i&15)*4;
    float4 v = *(const float4*)&ip[(size_t)(r0+r)*C + c0+c4];
    t[r][c4+0]=f2b(v.x); t[r][c4+1]=f2b(v.y); t[r][c4+2]=f2b(v.z); t[r][c4+3]=f2b(v.w);
  }
  __syncthreads();
  for (int i=threadIdx.x; i<1024; i+=256){
    int c = i>>4, r4 = (i&15)*4;
    bf16x4 v = { t[r4+0][c], t[r4+1][c], t[r4+2][c], t[r4+3][c] };
    *(bf16x4*)&op[(size_t)(c0+c)*R + r0+r4] = v;
  }
}

__global__ void chunk_mean_k(const float* __restrict__ x, short* __restrict__ cm){
  int idx = blockIdx.x*256 + threadIdx.x;     // B*N*D = 131072
  int d  = idx & (D_-1);
  int bn = idx >> 10;
  int b = bn >> 5, n = bn & 31;
  const float* p = x + ((size_t)b*S_ + n*CH_)*D_ + d;
  float s = 0.f;
  for (int ch=0; ch<CH_; ++ch) s += p[(size_t)ch*D_];
  cm[idx] = f2b(s * (1.f/CH_));
}

__global__ void gate_reduce_k(const float* __restrict__ Z, float* __restrict__ outp, float scale){
  int n = blockIdx.x;
  float s = 0.f;
  for (int b=0;b<B_;++b){
    const float* row = Z + (size_t)(b*N_+n)*D_;
    for (int j=threadIdx.x; j<D_; j+=256) s += row[j];
  }
  float tot = block_sum(s);
  if (threadIdx.x==0) outp[n] = scale * tot / (float)(B_*D_);
}

__global__ void rmsnorm2_k(const float* __restrict__ x, const float* __restrict__ gs,
                           const float* __restrict__ gr, short* __restrict__ xs, short* __restrict__ xr){
  size_t row = blockIdx.x;
  const float* xp = x + row*D_;
  float s = 0.f;
  for (int j=threadIdx.x;j<D_;j+=256){ float v=xp[j]; s+=v*v; }
  float tot = block_sum(s);
  float rinv = rsqrtf(tot/(float)D_ + EPS_);
  for (int j=threadIdx.x;j<D_;j+=256){
    float v = xp[j]*rinv;
    xs[row*D_+j] = f2b(v*gs[j]);
    xr[row*D_+j] = f2b(v*gr[j]);
  }
}

__global__ void l2norm_b(short* __restrict__ qk){
  size_t row = blockIdx.x;
  short* p = qk + row*D_;
  float s = 0.f;
  for (int j=threadIdx.x;j<D_;j+=256){ float v=b2f(p[j]); s+=v*v; }
  float tot = block_sum(s);
  float inv = 1.f / fmaxf(sqrtf(tot), 1e-12f);
  for (int j=threadIdx.x;j<D_;j+=256) p[j] = f2b(b2f(p[j])*inv);
}

__global__ void init_state_k(const float* __restrict__ W0, const float* __restrict__ W1,
                             float* __restrict__ W0c, float* __restrict__ W1c,
                             float* __restrict__ S0, float* __restrict__ S1,
                             short* __restrict__ W0b, short* __restrict__ W1b,
                             int* __restrict__ bar){
  size_t i = (size_t)blockIdx.x*256 + threadIdx.x;
  float a0=W0[i], a1=W1[i];
  W0c[i]=a0; W1c[i]=a1; S0[i]=0.f; S1[i]=0.f;
  W0b[i]=f2b(a0); W1b[i]=f2b(a1);
  if (i==0){ bar[0]=0; bar[1]=0; }
}

// ---------------- host ----------------
extern "C" void kernel_launch(void* const* d_in, const int* in_sizes, int n_in,
                              void* d_out, int out_size, void* d_ws, size_t ws_size,
                              hipStream_t stream) {
  (void)in_sizes; (void)n_in; (void)out_size;
  const float* x    = (const float*)d_in[0];
  const float* Mmet = (const float*)d_in[1];
  const float* Wk   = (const float*)d_in[2];
  const float* Wv   = (const float*)d_in[3];
  const float* Wq   = (const float*)d_in[4];
  const float* Wo   = (const float*)d_in[5];
  const float* Wgd  = (const float*)d_in[6];
  const float* bgd  = (const float*)d_in[7];
  const float* Wgl  = (const float*)d_in[8];
  const float* bgl  = (const float*)d_in[9];
  const float* Wgm  = (const float*)d_in[10];
  const float* bgm  = (const float*)d_in[11];
  const float* g_store = (const float*)d_in[12];
  const float* g_retr  = (const float*)d_in[13];
  const float* W0   = (const float*)d_in[14];
  const float* W1   = (const float*)d_in[15];
  float* out = (float*)d_out;

  if (ws_size < 166000000ull) return;   // layout below ~= 154 MB
  short* qk    = (short*)d_ws;          // [N,512,D] q rows 0..255, k rows 256..511
  short* vbuf  = qk    + 16777216;      // [N,256,D]
  short* xs    = vbuf  + 8388608;       // [B*S,D]
  short* xr    = xs    + 8388608;       // [B*S,D]  -> reused as ktT [N,1024,256]
  short* t1    = xr    + 8388608;       // [B*S,D]  -> reused as preout
  short* cm    = t1    + 8388608;       // [128,D]
  short* Wkb   = cm    + 131072;
  short* Wvb   = Wkb   + 1048576;
  short* Wqb   = Wvb   + 1048576;
  short* Wob   = Wqb   + 1048576;
  short* Wgdb  = Wob   + 1048576;
  short* Wglb  = Wgdb  + 1048576;
  short* Wgmb  = Wglb  + 1048576;
  short* MmetT = Wgmb  + 1048576;       // [B,D,D] transposed (bf16)
  short* W0b   = MmetT + 4194304;
  short* W1b   = W0b   + 1048576;
  short* W1bT0 = W1b   + 1048576;
  short* W1bT1 = W1bT0 + 1048576;
  short* abuf  = W1bT1 + 1048576;       // [512,D]
  short* akT   = abuf  + 524288;        // [D,256]
  short* dpred = akT   + 262144;        // [256,D]
  short* dpredT= dpred + 262144;        // [D,256]
  short* dh1T  = dpredT+ 262144;        // [D,256]
  float* Zg    = (float*)(dh1T + 262144);  // [128,D]
  float* gates = Zg    + 131072;        // [96]
  float* hkT   = gates + 128;           // [D,256]
  float* W0c   = hkT   + 262144;
  float* W1c   = W0c   + 1048576;
  float* S0m   = W1c   + 1048576;
  float* S1m   = S0m   + 1048576;
  int*   bar   = (int*)(S1m + 1048576);
  short* ktT   = xr;                    // alias (xr dead before ktT written)
  short* preout= t1;                    // alias (t1 dead before scan)

  // conversions / init / static transposes
  conv_k<<<1024,256,0,stream>>>(Wk,  Wkb,  262144);
  conv_k<<<1024,256,0,stream>>>(Wv,  Wvb,  262144);
  conv_k<<<1024,256,0,stream>>>(Wq,  Wqb,  262144);
  conv_k<<<1024,256,0,stream>>>(Wo,  Wob,  262144);
  conv_k<<<1024,256,0,stream>>>(Wgd, Wgdb, 262144);
  conv_k<<<1024,256,0,stream>>>(Wgl, Wglb, 262144);
  conv_k<<<1024,256,0,stream>>>(Wgm, Wgmb, 262144);
  transpose_f2b_k<<<dim3(16,16,4),256,0,stream>>>(Mmet, MmetT, 1024, 1024, 1048576, 1048576);
  init_state_k<<<4096,256,0,stream>>>(W0, W1, W0c, W1c, S0m, S1m, W0b, W1b, bar);
  transpose_bf_k<<<dim3(16,16,1),256,0,stream>>>(W1b, W1bT0, 1024, 1024, 0, 0);

  // chunk means + gates
  chunk_mean_k<<<512,256,0,stream>>>(x, cm);
  {
    dim3 g(8,1);
    mgemm<2,2,EpiBiasSig><<<g,256,0,stream>>>(cm, Wgdb, 1024,1024,1024, EpiBiasSig{Zg, bgd});
    gate_reduce_k<<<N_,256,0,stream>>>(Zg, gates + 0,    0.01f);   // MEM_DECAY
    mgemm<2,2,EpiBiasSig><<<g,256,0,stream>>>(cm, Wglb, 1024,1024,1024, EpiBiasSig{Zg, bgl});
    gate_reduce_k<<<N_,256,0,stream>>>(Zg, gates + N_,   0.1f);    // MEM_LR
    mgemm<2,2,EpiBiasSig><<<g,256,0,stream>>>(cm, Wgmb, 1024,1024,1024, EpiBiasSig{Zg, bgm});
    gate_reduce_k<<<N_,256,0,stream>>>(Zg, gates + 2*N_, 0.9f);    // MEM_MOM
  }
  // dual RMSNorm
  rmsnorm2_k<<<B_*S_,256,0,stream>>>(x, g_store, g_retr, xs, xr);
  // t1 = xs @ Mmet[b]  (B = MmetT[b] mode0)
  for (int b=0;b<B_;++b)
    mgemm<2,2,EpiStoreBf><<<dim3(8,16),256,0,stream>>>(
      xs + (size_t)b*S_*D_, MmetT + (size_t)b*D_*D_, 1024,1024,1024,
      EpiStoreBf{t1 + (size_t)b*S_*D_});
  // k, v, q projections with silu + chunk scatter
  {
    dim3 g(8,64);
    mgemm<2,2,EpiScat><<<g,256,0,stream>>>(t1, Wkb, 1024,1024,1024, EpiScat{qk, 1});
    mgemm<2,2,EpiScat><<<g,256,0,stream>>>(xs, Wvb, 1024,1024,1024, EpiScat{vbuf,-1});
    mgemm<2,2,EpiScat><<<g,256,0,stream>>>(xr, Wqb, 1024,1024,1024, EpiScat{qk, 0});
  }
  l2norm_b<<<N_*512,256,0,stream>>>(qk);
  // ktT[t][i][r] = qk[t][256+r][i]  (k rows, per chunk)
  transpose_bf_k<<<dim3(16,4,32),256,0,stream>>>(qk + 256*1024, ktT, 256, 1024,
                                                 (size_t)512*1024, (size_t)1024*256);

  // persistent scan (one launch, relaxed monotonic grid barrier, sc1 shared data)
  scan_coop<<<GRID_,256,0,stream>>>(qk, vbuf, ktT, gates, preout, hkT, abuf, akT,
                                    dpred, dpredT, dh1T, W0c, W1c, S0m, S1m,
                                    W0b, W1b, W1bT0, W1bT1, bar);

  // out = preout @ Wo^T
  mgemm<2,2,EpiOut><<<dim3(8,64),256,0,stream>>>(preout, Wob, 1024,1024,1024, EpiOut{out});
}

// Round 6
// 5121.138 us; speedup vs baseline: 1.9442x; 1.4486x over previous
//
#include <hip/hip_runtime.h>
#include <math.h>

static constexpr int B_ = 4, S_ = 2048, D_ = 1024, CH_ = 64, N_ = 32;
static constexpr float EPS_ = 1.1920929e-07f;
static constexpr float C2_  = 2.0f / 262144.0f;   // 2/(B*CH*D)
static constexpr int GRID_ = 80;                  // scan grid (<=256 CUs -> co-resident)
static constexpr int SC_   = 0x11;                // CPol sc0|sc1: coherence-point access

typedef __attribute__((ext_vector_type(8))) short bf16x8;
typedef __attribute__((ext_vector_type(4))) short bf16x4;
typedef __attribute__((ext_vector_type(4))) float f32x4;

__device__ __forceinline__ float sigf(float x)  { return 1.f/(1.f+expf(-x)); }
__device__ __forceinline__ float siluf(float x) { return x/(1.f+expf(-x)); }
__device__ __forceinline__ float silugrad(float x){
  float s = 1.f/(1.f+expf(-x));
  return s*(1.f + x*(1.f-s));
}
__device__ __forceinline__ short f2b(float f){
  union{float f;unsigned u;}c; c.f=f;
  unsigned u=c.u;
  return (short)((u + 0x7fffu + ((u>>16)&1u)) >> 16);   // RNE
}
__device__ __forceinline__ float b2f(short h){
  union{unsigned u;float f;}c; c.u=((unsigned)(unsigned short)h)<<16; return c.f;
}

// coherence-point accesses (sc0|sc1): cross-block data inside the persistent scan.
__device__ __forceinline__ void st_sys16(short* p, short v){
  __hip_atomic_store(p, v, __ATOMIC_RELAXED, __HIP_MEMORY_SCOPE_SYSTEM); }
__device__ __forceinline__ short ld_sys16(const short* p){
  return __hip_atomic_load(p, __ATOMIC_RELAXED, __HIP_MEMORY_SCOPE_SYSTEM); }
__device__ __forceinline__ void st_sys64(short* p, bf16x4 v){
  unsigned long long u; __builtin_memcpy(&u, &v, 8);
  __hip_atomic_store((unsigned long long*)p, u, __ATOMIC_RELAXED, __HIP_MEMORY_SCOPE_SYSTEM); }

__device__ __forceinline__ void wait_vm(int c){   // c = stages-in-flight-1, LPS=8
  if (c == 0)      asm volatile("s_waitcnt vmcnt(0)"  ::: "memory");
  else if (c == 1) asm volatile("s_waitcnt vmcnt(8)"  ::: "memory");
  else             asm volatile("s_waitcnt vmcnt(16)" ::: "memory");
}

// ---------------- GEMM core: C[m,n] = sum_k A[m,k]*B[n,k], operands row-major [dim,K] ----------
// 128x128 tile, 4 waves (2x2). BK=64, DEPTH-buffered LDS (T3/T4: counted vmcnt, raw s_barrier,
// never drains to 0 mid-loop). Source-side chunk swizzle sc = cc ^ (row&7) with matching read
// swizzle -> 2-way max bank conflict (free). AAUX/BAUX: 0 = cached, SC_ = coherence-point.
template<int WMW, int WNW, int DEPTH, int AAUX, int BAUX, class Epi>
__device__ __forceinline__ void gemm_core(
    const short* __restrict__ A, const short* __restrict__ Bm,
    int K, int lda, int ldb, int bm0, int bn0, short* lds, Epi epi)
{
  constexpr int BK = 64, CPR = 8;                    // 16B chunks per row
  constexpr int BMR = WMW*64, BNR = WNW*64, T = WMW*WNW*64;
  constexpr int ACH = BMR*CPR, BCH = BNR*CPR;
  constexpr int BUF = (BMR+BNR)*BK;                  // shorts per buffer
  static_assert((ACH+BCH)/T == 8, "LPS must be 8 for wait_vm");
  const int tid = threadIdx.x, lane = tid & 63, w = tid >> 6;
  const int wm = w / WNW, wn = w % WNW, lrow = lane & 15, lk8 = lane >> 4;

  f32x4 acc[4][4];
  #pragma unroll
  for (int i=0;i<4;++i)
    #pragma unroll
    for (int j=0;j<4;++j) acc[i][j] = (f32x4){0.f,0.f,0.f,0.f};

  auto stage = [&](int s){
    short* la = lds + (s & (DEPTH-1))*BUF;
    short* lb = la + BMR*BK;
    const int k0 = s*BK;
    #pragma unroll
    for (int i=tid; i<ACH; i+=T){
      int row = i>>3, sc = (i&7) ^ (row&7);
      const short* src = A + (size_t)(bm0+row)*lda + k0 + (sc<<3);
      __builtin_amdgcn_global_load_lds(
        (const __attribute__((address_space(1))) void*)src,
        (__attribute__((address_space(3))) void*)(la + i*8), 16, 0, AAUX);
    }
    #pragma unroll
    for (int i=tid; i<BCH; i+=T){
      int row = i>>3, sc = (i&7) ^ (row&7);
      const short* src = Bm + (size_t)(bn0+row)*ldb + k0 + (sc<<3);
      __builtin_amdgcn_global_load_lds(
        (const __attribute__((address_space(1))) void*)src,
        (__attribute__((address_space(3))) void*)(lb + i*8), 16, 0, BAUX);
    }
  };

  const int nk = K >> 6;
  for (int s=0; s<DEPTH-1 && s<nk; ++s) stage(s);
  for (int ks=0; ks<nk; ++ks){
    int C = nk - ks; if (C > DEPTH-1) C = DEPTH-1;   // stages in flight before barrier
    wait_vm(C-1);                                    // stage ks landed (this wave)
    __builtin_amdgcn_s_barrier();                    // all waves' stage ks landed
    __builtin_amdgcn_sched_barrier(0);
    if (ks + DEPTH-1 < nk) stage(ks + DEPTH-1);      // refill pipeline (post-barrier: safe)
    short* la = lds + (ks & (DEPTH-1))*BUF;
    short* lb = la + BMR*BK;
    #pragma unroll
    for (int kk=0; kk<2; ++kk){
      bf16x8 af[4], bfr[4];
      #pragma unroll
      for (int mi=0;mi<4;++mi){
        int row = wm*64 + mi*16 + lrow;
        int ch = row*8 + ((kk*4+lk8) ^ (row&7));
        af[mi] = *(const bf16x8*)(la + ch*8);
      }
      #pragma unroll
      for (int ni=0;ni<4;++ni){
        int row = wn*64 + ni*16 + lrow;
        int ch = row*8 + ((kk*4+lk8) ^ (row&7));
        bfr[ni] = *(const bf16x8*)(lb + ch*8);
      }
      #pragma unroll
      for (int mi=0;mi<4;++mi)
        #pragma unroll
        for (int ni=0;ni<4;++ni)
          acc[mi][ni] = __builtin_amdgcn_mfma_f32_16x16x32_bf16(af[mi], bfr[ni], acc[mi][ni], 0,0,0);
    }
  }
  // quad epilogue: rows r0..r0+3 (M-dir), fixed col
  #pragma unroll
  for (int mi=0;mi<4;++mi)
    #pragma unroll
    for (int ni=0;ni<4;++ni)
      epi(bm0 + wm*64 + mi*16 + lk8*4, bn0 + wn*64 + ni*16 + lrow, acc[mi][ni]);
}

// ---------------- epilogue functors (quad: rows r0..r0+3, col c) ----------------
struct EpiOut { float* C;
  __device__ void operator()(int r0,int c,f32x4 q) const {
    #pragma unroll
    for (int j=0;j<4;++j) C[(size_t)(r0+j)*D_+c]=q[j]; } };

struct EpiStoreBf { short* C;
  __device__ void operator()(int r0,int c,f32x4 q) const {
    #pragma unroll
    for (int j=0;j<4;++j) C[(size_t)(r0+j)*D_+c]=f2b(q[j]); } };

struct EpiBiasSig { float* C; const float* bias;
  __device__ void operator()(int r0,int c,f32x4 q) const {
    #pragma unroll
    for (int j=0;j<4;++j) C[(size_t)(r0+j)*D_+c] = sigf(q[j] + bias[c]); } };

struct EpiScat { short* dst; int part;   // -1: v[N,256,D]; 0: q rows; 1: k rows of qk[N,512,D]
  __device__ void operator()(int r0,int c,f32x4 q) const {
    #pragma unroll
    for (int j=0;j<4;++j){
      int r = r0+j;
      int b = r >> 11, s = r & 2047, t = s >> 6, ch = s & 63;
      short sv = f2b(siluf(q[j]));
      if (part < 0) dst[((size_t)t*256 +             b*64 + ch)*D_ + c] = sv;
      else          dst[((size_t)t*512 + part*256 + b*64 + ch)*D_ + c] = sv;
    } } };

template<int WMW, int WNW, class Epi>
__global__ __launch_bounds__(WMW*WNW*64)
void mgemm(const short* __restrict__ A, const short* __restrict__ Bm,
           int K, int lda, int ldb, Epi epi){
  __shared__ __align__(16) short lds[2*(WMW+WNW)*64*64];   // DEPTH=2, BK=64
  gemm_core<WMW,WNW,2,0,0>(A, Bm, K, lda, ldb, blockIdx.y*WMW*64, blockIdx.x*WNW*64, lds, epi);
}

// ---------------- grid barrier: relaxed monotonic counter (no cache maintenance) -------------
__device__ __forceinline__ void gsync(int* cnt, int target){
  asm volatile("s_waitcnt vmcnt(0) lgkmcnt(0)" ::: "memory");  // sc1 stores at coherence point
  __syncthreads();
  if (threadIdx.x == 0){
    __hip_atomic_fetch_add(cnt, 1, __ATOMIC_RELAXED, __HIP_MEMORY_SCOPE_AGENT);
    while (__hip_atomic_load(cnt, __ATOMIC_RELAXED, __HIP_MEMORY_SCOPE_AGENT) < target)
      __builtin_amdgcn_s_sleep(4);
  }
  __syncthreads();
}

// ---------------- persistent scan kernel ----------------
// Masters (W0c,W1c,S0m,S1m): block-private (fixed tile ownership) -> cached float4.
// Shared step data (W-mirrors, activations): sc0|sc1 both sides, 8B vectorized where contiguous.
__global__ __launch_bounds__(256)
void scan_coop(const short* __restrict__ qk, const short* __restrict__ vbuf,
               const short* __restrict__ ktT, const float* __restrict__ gates,
               short* __restrict__ preout, short* __restrict__ sgT,
               short* __restrict__ abuf, short* __restrict__ akT,
               short* __restrict__ dpred, short* __restrict__ dpredT, short* __restrict__ dh1T,
               float* __restrict__ W0c, float* __restrict__ W1c,
               float* __restrict__ S0m, float* __restrict__ S1m,
               short* __restrict__ W0b, short* __restrict__ W1b,
               short* __restrict__ W1bT0, short* __restrict__ W1bT1,
               int* __restrict__ bar)
{
  __shared__ __align__(16) short lds[4*(2+2)*64*64];   // DEPTH=4, 128 KB
  const int bid = blockIdx.x;
  int* cnt = bar;
  int ep = 0;

  for (int t=0; t<N_; ++t){
    const short* qkt = qk + (size_t)t*512*D_;
    const float al = gates[t], th = gates[N_+t], et = gates[2*N_+t];
    short* W1Tcur = (t&1) ? W1bT1 : W1bT0;
    short* W1Tnxt = (t&1) ? W1bT0 : W1bT1;

    // P1: h = [q;k] @ W0^T  -> abuf = silu(h); k rows also -> akT, sgT (transposed)
    if (bid < 32){
      int bm0=(bid>>3)*128, bn0=(bid&7)*128;
      gemm_core<2,2,4,0,SC_>(qkt, W0b, 1024, 1024, 1024, bm0, bn0, lds,
        [&](int r0,int c,f32x4 q){
          bf16x4 a4, g4;
          #pragma unroll
          for (int j=0;j<4;++j){
            a4[j] = f2b(siluf(q[j]));
            g4[j] = f2b(silugrad(q[j]));
            st_sys16(&abuf[(size_t)(r0+j)*D_+c], a4[j]);
          }
          if (r0 >= 256){ int rr = r0-256;
            st_sys64(&akT[(size_t)c*256+rr], a4);
            st_sys64(&sgT[(size_t)c*256+rr], g4); }
        });
    }
    gsync(cnt, (++ep)*GRID_);

    // P2: pred = a @ W1^T -> retrieve (q rows) + dpred/dpredT (k rows)
    if (bid < 32){
      int bm0=(bid>>3)*128, bn0=(bid&7)*128;
      const short* vt = vbuf + (size_t)t*256*D_;
      gemm_core<2,2,4,SC_,SC_>(abuf, W1b, 1024, 1024, 1024, bm0, bn0, lds,
        [&](int r0,int c,f32x4 q){
          if (r0 < 256){
            #pragma unroll
            for (int j=0;j<4;++j){ int r=r0+j, b=r>>6, ch=r&63;
              preout[((size_t)b*S_ + t*CH_ + ch)*D_ + c] = f2b(q[j]); }
          } else { int rr = r0-256;
            bf16x4 d4;
            #pragma unroll
            for (int j=0;j<4;++j){
              float dv = C2_*(q[j] - b2f(vt[(size_t)(rr+j)*D_+c]));
              d4[j] = f2b(dv);
              st_sys16(&dpred[(size_t)(rr+j)*D_+c], d4[j]);
            }
            st_sys64(&dpredT[(size_t)c*256+rr], d4); }
        });
    }
    gsync(cnt, (++ep)*GRID_);
    if (t == N_-1) break;   // last step: retrieval only

    // P3a (bid<16): dh1T[h,r] = (sum_o W1T[h,o] dpred[r,o]) * sgT[h,r]
    // P3b (16<=bid<80): g1T[h,o] = sum_r akT[h,r] dpredT[o,r]; fused W1 update
    if (bid < 16){
      int bm0=(bid>>1)*128, bn0=(bid&1)*128;
      gemm_core<2,2,4,SC_,SC_>(W1Tcur, dpred, 1024, 1024, 1024, bm0, bn0, lds,
        [&](int r0,int c,f32x4 q){
          #pragma unroll
          for (int j=0;j<4;++j){
            size_t i=(size_t)(r0+j)*256+c;
            st_sys16(&dh1T[i], f2b(q[j] * b2f(ld_sys16(&sgT[i]))));
          }
        });
    } else if (bid < 80){
      int qd=bid-16, bm0=(qd>>3)*128, bn0=(qd&7)*128;   // rows=h, cols=o
      gemm_core<2,2,4,SC_,SC_>(akT, dpredT, 256, 256, 256, bm0, bn0, lds,
        [&](int r0,int c,f32x4 q){
          size_t mi = (size_t)c*D_ + r0;                 // masters W1[o,h]: h-quad contiguous
          f32x4 s4 = *(f32x4*)&S1m[mi];
          f32x4 w4 = *(f32x4*)&W1c[mi];
          bf16x4 nb;
          #pragma unroll
          for (int j=0;j<4;++j){
            float s = et*s4[j] - th*q[j];
            s4[j] = s;
            float wv = (1.f-al)*w4[j] + s;
            w4[j] = wv; nb[j] = f2b(wv);
          }
          *(f32x4*)&S1m[mi] = s4; *(f32x4*)&W1c[mi] = w4;
          st_sys64(&W1b[mi], nb);
          #pragma unroll
          for (int j=0;j<4;++j) st_sys16(&W1Tnxt[(size_t)(r0+j)*D_ + c], nb[j]);
        });
    }
    gsync(cnt, (++ep)*GRID_);

    // P4: g0T[i,h] = sum_r ktT[i,r] dh1T[h,r]; fused W0 update (rows=i, cols=h)
    if (bid < 64){
      int bm0=(bid>>3)*128, bn0=(bid&7)*128;
      gemm_core<2,2,4,0,SC_>(ktT + (size_t)t*D_*256, dh1T, 256, 256, 256, bm0, bn0, lds,
        [&](int r0,int c,f32x4 q){
          size_t mi = (size_t)c*D_ + r0;                 // masters W0[h,i]: i-quad contiguous
          f32x4 s4 = *(f32x4*)&S0m[mi];
          f32x4 w4 = *(f32x4*)&W0c[mi];
          bf16x4 nb;
          #pragma unroll
          for (int j=0;j<4;++j){
            float s = et*s4[j] - th*q[j];
            s4[j] = s;
            float wv = (1.f-al)*w4[j] + s;
            w4[j] = wv; nb[j] = f2b(wv);
          }
          *(f32x4*)&S0m[mi] = s4; *(f32x4*)&W0c[mi] = w4;
          st_sys64(&W0b[mi], nb);
        });
    }
    gsync(cnt, (++ep)*GRID_);
  }
}

// ---------------- small kernels ----------------
__device__ __forceinline__ float block_sum(float v){
  #pragma unroll
  for (int o=32;o>0;o>>=1) v += __shfl_down(v,o,64);
  __shared__ float sm4[4];
  int lane = threadIdx.x & 63, w = threadIdx.x >> 6;
  if (lane==0) sm4[w]=v;
  __syncthreads();
  float r = sm4[0]+sm4[1]+sm4[2]+sm4[3];
  __syncthreads();
  return r;
}

__global__ void conv_k(const float* __restrict__ s, short* __restrict__ d, int n4){
  int i = blockIdx.x*256 + threadIdx.x;
  if (i >= n4) return;
  float4 v = ((const float4*)s)[i];
  bf16x4 o = { f2b(v.x), f2b(v.y), f2b(v.z), f2b(v.w) };
  ((bf16x4*)d)[i] = o;
}

__global__ __launch_bounds__(256)
void transpose_bf_k(const short* __restrict__ in, short* __restrict__ out,
                    int R, int C, size_t ibs, size_t obs){
  __shared__ short t[64][68];
  const short* ip = in + blockIdx.z*ibs;
  short* op = out + blockIdx.z*obs;
  int r0 = blockIdx.y*64, c0 = blockIdx.x*64;
  for (int i=threadIdx.x; i<1024; i+=256){
    int r = i>>4, c4 = (i&15)*4;
    *(bf16x4*)&t[r][c4] = *(const bf16x4*)&ip[(size_t)(r0+r)*C + c0+c4];
  }
  __syncthreads();
  for (int i=threadIdx.x; i<1024; i+=256){
    int c = i>>4, r4 = (i&15)*4;
    bf16x4 v = { t[r4+0][c], t[r4+1][c], t[r4+2][c], t[r4+3][c] };
    *(bf16x4*)&op[(size_t)(c0+c)*R + r0+r4] = v;
  }
}

__global__ __launch_bounds__(256)
void transpose_f2b_k(const float* __restrict__ in, short* __restrict__ out,
                     int R, int C, size_t ibs, size_t obs){
  __shared__ short t[64][68];
  const float* ip = in + blockIdx.z*ibs;
  short* op = out + blockIdx.z*obs;
  int r0 = blockIdx.y*64, c0 = blockIdx.x*64;
  for (int i=threadIdx.x; i<1024; i+=256){
    int r = i>>4, c4 = (i&15)*4;
    float4 v = *(const float4*)&ip[(size_t)(r0+r)*C + c0+c4];
    t[r][c4+0]=f2b(v.x); t[r][c4+1]=f2b(v.y); t[r][c4+2]=f2b(v.z); t[r][c4+3]=f2b(v.w);
  }
  __syncthreads();
  for (int i=threadIdx.x; i<1024; i+=256){
    int c = i>>4, r4 = (i&15)*4;
    bf16x4 v = { t[r4+0][c], t[r4+1][c], t[r4+2][c], t[r4+3][c] };
    *(bf16x4*)&op[(size_t)(c0+c)*R + r0+r4] = v;
  }
}

__global__ void chunk_mean_k(const float* __restrict__ x, short* __restrict__ cm){
  int idx = blockIdx.x*256 + threadIdx.x;     // B*N*D = 131072
  int d  = idx & (D_-1);
  int bn = idx >> 10;
  int b = bn >> 5, n = bn & 31;
  const float* p = x + ((size_t)b*S_ + n*CH_)*D_ + d;
  float s = 0.f;
  for (int ch=0; ch<CH_; ++ch) s += p[(size_t)ch*D_];
  cm[idx] = f2b(s * (1.f/CH_));
}

__global__ void gate_reduce_k(const float* __restrict__ Z, float* __restrict__ outp, float scale){
  int n = blockIdx.x;
  float s = 0.f;
  for (int b=0;b<B_;++b){
    const float* row = Z + (size_t)(b*N_+n)*D_;
    for (int j=threadIdx.x; j<D_; j+=256) s += row[j];
  }
  float tot = block_sum(s);
  if (threadIdx.x==0) outp[n] = scale * tot / (float)(B_*D_);
}

__global__ void rmsnorm2_k(const float* __restrict__ x, const float* __restrict__ gs,
                           const float* __restrict__ gr, short* __restrict__ xs, short* __restrict__ xr){
  size_t row = blockIdx.x;
  const float* xp = x + row*D_;
  float s = 0.f;
  for (int j=threadIdx.x;j<D_;j+=256){ float v=xp[j]; s+=v*v; }
  float tot = block_sum(s);
  float rinv = rsqrtf(tot/(float)D_ + EPS_);
  for (int j=threadIdx.x;j<D_;j+=256){
    float v = xp[j]*rinv;
    xs[row*D_+j] = f2b(v*gs[j]);
    xr[row*D_+j] = f2b(v*gr[j]);
  }
}

__global__ void l2norm_b(short* __restrict__ qk){
  size_t row = blockIdx.x;
  short* p = qk + row*D_;
  float s = 0.f;
  for (int j=threadIdx.x;j<D_;j+=256){ float v=b2f(p[j]); s+=v*v; }
  float tot = block_sum(s);
  float inv = 1.f / fmaxf(sqrtf(tot), 1e-12f);
  for (int j=threadIdx.x;j<D_;j+=256) p[j] = f2b(b2f(p[j])*inv);
}

__global__ void init_state_k(const float* __restrict__ W0, const float* __restrict__ W1,
                             float* __restrict__ W0c, float* __restrict__ W1c,
                             float* __restrict__ S0, float* __restrict__ S1,
                             short* __restrict__ W0b, short* __restrict__ W1b,
                             int* __restrict__ bar){
  size_t i = (size_t)blockIdx.x*256 + threadIdx.x;
  float a0=W0[i], a1=W1[i];
  W0c[i]=a0; W1c[i]=a1; S0[i]=0.f; S1[i]=0.f;
  W0b[i]=f2b(a0); W1b[i]=f2b(a1);
  if (i==0){ bar[0]=0; bar[1]=0; }
}

// ---------------- host ----------------
extern "C" void kernel_launch(void* const* d_in, const int* in_sizes, int n_in,
                              void* d_out, int out_size, void* d_ws, size_t ws_size,
                              hipStream_t stream) {
  (void)in_sizes; (void)n_in; (void)out_size;
  const float* x    = (const float*)d_in[0];
  const float* Mmet = (const float*)d_in[1];
  const float* Wk   = (const float*)d_in[2];
  const float* Wv   = (const float*)d_in[3];
  const float* Wq   = (const float*)d_in[4];
  const float* Wo   = (const float*)d_in[5];
  const float* Wgd  = (const float*)d_in[6];
  const float* bgd  = (const float*)d_in[7];
  const float* Wgl  = (const float*)d_in[8];
  const float* bgl  = (const float*)d_in[9];
  const float* Wgm  = (const float*)d_in[10];
  const float* bgm  = (const float*)d_in[11];
  const float* g_store = (const float*)d_in[12];
  const float* g_retr  = (const float*)d_in[13];
  const float* W0   = (const float*)d_in[14];
  const float* W1   = (const float*)d_in[15];
  float* out = (float*)d_out;

  if (ws_size < 160000000ull) return;   // layout below ~= 153.5 MB
  short* qk    = (short*)d_ws;          // [N,512,D] q rows 0..255, k rows 256..511
  short* vbuf  = qk    + 16777216;      // [N,256,D]
  short* xs    = vbuf  + 8388608;       // [B*S,D]
  short* xr    = xs    + 8388608;       // [B*S,D]  -> reused as ktT [N,1024,256]
  short* t1    = xr    + 8388608;       // [B*S,D]  -> reused as preout
  short* cm    = t1    + 8388608;       // [128,D]
  short* Wkb   = cm    + 131072;
  short* Wvb   = Wkb   + 1048576;
  short* Wqb   = Wvb   + 1048576;
  short* Wob   = Wqb   + 1048576;
  short* Wgdb  = Wob   + 1048576;
  short* Wglb  = Wgdb  + 1048576;
  short* Wgmb  = Wglb  + 1048576;
  short* MmetT = Wgmb  + 1048576;       // [B,D,D] transposed (bf16)
  short* W0b   = MmetT + 4194304;
  short* W1b   = W0b   + 1048576;
  short* W1bT0 = W1b   + 1048576;
  short* W1bT1 = W1bT0 + 1048576;
  short* abuf  = W1bT1 + 1048576;       // [512,D]
  short* akT   = abuf  + 524288;        // [D,256]
  short* sgT   = akT   + 262144;        // [D,256] silu'(h_k) bf16
  short* dpred = sgT   + 262144;        // [256,D]
  short* dpredT= dpred + 262144;        // [D,256]
  short* dh1T  = dpredT+ 262144;        // [D,256]
  float* Zg    = (float*)(dh1T + 262144);  // [128,D]
  float* gates = Zg    + 131072;        // [96]
  float* W0c   = gates + 128;
  float* W1c   = W0c   + 1048576;
  float* S0m   = W1c   + 1048576;
  float* S1m   = S0m   + 1048576;
  int*   bar   = (int*)(S1m + 1048576);
  short* ktT   = xr;                    // alias (xr dead before ktT written)
  short* preout= t1;                    // alias (t1 dead before scan)

  // conversions / init / static transposes
  conv_k<<<1024,256,0,stream>>>(Wk,  Wkb,  262144);
  conv_k<<<1024,256,0,stream>>>(Wv,  Wvb,  262144);
  conv_k<<<1024,256,0,stream>>>(Wq,  Wqb,  262144);
  conv_k<<<1024,256,0,stream>>>(Wo,  Wob,  262144);
  conv_k<<<1024,256,0,stream>>>(Wgd, Wgdb, 262144);
  conv_k<<<1024,256,0,stream>>>(Wgl, Wglb, 262144);
  conv_k<<<1024,256,0,stream>>>(Wgm, Wgmb, 262144);
  transpose_f2b_k<<<dim3(16,16,4),256,0,stream>>>(Mmet, MmetT, 1024, 1024, 1048576, 1048576);
  init_state_k<<<4096,256,0,stream>>>(W0, W1, W0c, W1c, S0m, S1m, W0b, W1b, bar);
  transpose_bf_k<<<dim3(16,16,1),256,0,stream>>>(W1b, W1bT0, 1024, 1024, 0, 0);

  // chunk means + gates
  chunk_mean_k<<<512,256,0,stream>>>(x, cm);
  {
    dim3 g(8,1);
    mgemm<2,2,EpiBiasSig><<<g,256,0,stream>>>(cm, Wgdb, 1024,1024,1024, EpiBiasSig{Zg, bgd});
    gate_reduce_k<<<N_,256,0,stream>>>(Zg, gates + 0,    0.01f);   // MEM_DECAY
    mgemm<2,2,EpiBiasSig><<<g,256,0,stream>>>(cm, Wglb, 1024,1024,1024, EpiBiasSig{Zg, bgl});
    gate_reduce_k<<<N_,256,0,stream>>>(Zg, gates + N_,   0.1f);    // MEM_LR
    mgemm<2,2,EpiBiasSig><<<g,256,0,stream>>>(cm, Wgmb, 1024,1024,1024, EpiBiasSig{Zg, bgm});
    gate_reduce_k<<<N_,256,0,stream>>>(Zg, gates + 2*N_, 0.9f);    // MEM_MOM
  }
  // dual RMSNorm
  rmsnorm2_k<<<B_*S_,256,0,stream>>>(x, g_store, g_retr, xs, xr);
  // t1 = xs @ Mmet[b]
  for (int b=0;b<B_;++b)
    mgemm<2,2,EpiStoreBf><<<dim3(8,16),256,0,stream>>>(
      xs + (size_t)b*S_*D_, MmetT + (size_t)b*D_*D_, 1024,1024,1024,
      EpiStoreBf{t1 + (size_t)b*S_*D_});
  // k, v, q projections with silu + chunk scatter
  {
    dim3 g(8,64);
    mgemm<2,2,EpiScat><<<g,256,0,stream>>>(t1, Wkb, 1024,1024,1024, EpiScat{qk, 1});
    mgemm<2,2,EpiScat><<<g,256,0,stream>>>(xs, Wvb, 1024,1024,1024, EpiScat{vbuf,-1});
    mgemm<2,2,EpiScat><<<g,256,0,stream>>>(xr, Wqb, 1024,1024,1024, EpiScat{qk, 0});
  }
  l2norm_b<<<N_*512,256,0,stream>>>(qk);
  // ktT[t][i][r] = qk[t][256+r][i]
  transpose_bf_k<<<dim3(16,4,32),256,0,stream>>>(qk + 256*1024, ktT, 256, 1024,
                                                 (size_t)512*1024, (size_t)1024*256);

  // persistent scan
  scan_coop<<<GRID_,256,0,stream>>>(qk, vbuf, ktT, gates, preout, sgT, abuf, akT,
                                    dpred, dpredT, dh1T, W0c, W1c, S0m, S1m,
                                    W0b, W1b, W1bT0, W1bT1, bar);

  // out = preout @ Wo^T
  mgemm<2,2,EpiOut><<<dim3(8,64),256,0,stream>>>(preout, Wob, 1024,1024,1024, EpiOut{out});
}

// Round 7
// 4606.371 us; speedup vs baseline: 2.1614x; 1.1118x over previous
//
#include <hip/hip_runtime.h>
#include <math.h>

static constexpr int B_ = 4, S_ = 2048, D_ = 1024, CH_ = 64, N_ = 32;
static constexpr float EPS_ = 1.1920929e-07f;
static constexpr float C2_  = 2.0f / 262144.0f;   // 2/(B*CH*D)
static constexpr int GRID_ = 80;                  // scan grid (<=256 CUs -> co-resident)

typedef __attribute__((ext_vector_type(8))) short bf16x8;
typedef __attribute__((ext_vector_type(4))) short bf16x4;
typedef __attribute__((ext_vector_type(4))) float f32x4;

__device__ __forceinline__ float sigf(float x)  { return 1.f/(1.f+expf(-x)); }
__device__ __forceinline__ float siluf(float x) { return x/(1.f+expf(-x)); }
__device__ __forceinline__ float silugrad(float x){
  float s = 1.f/(1.f+expf(-x));
  return s*(1.f + x*(1.f-s));
}
__device__ __forceinline__ short f2b(float f){
  union{float f;unsigned u;}c; c.f=f;
  unsigned u=c.u;
  return (short)((u + 0x7fffu + ((u>>16)&1u)) >> 16);   // RNE
}
__device__ __forceinline__ float b2f(short h){
  union{unsigned u;float f;}c; c.u=((unsigned)(unsigned short)h)<<16; return c.f;
}

template<int LPS>
__device__ __forceinline__ void wait_vm(int c){   // c = in-flight stages - 1
  if (c <= 0)      asm volatile("s_waitcnt vmcnt(0)" ::: "memory");
  else if (c == 1) asm volatile("s_waitcnt vmcnt(%0)" :: "i"(LPS)   : "memory");
  else             asm volatile("s_waitcnt vmcnt(%0)" :: "i"(2*LPS) : "memory");
}

// ---------------- GEMM core: C[m,n] = sum_k A[m,k]*B[n,k], operands row-major [dim,K] ----------
// 128x128 tile, 4 waves (2x2). BK=64, DEPTH-buffered LDS (counted vmcnt, raw s_barrier, never
// drains mid-loop). Source-side chunk swizzle sc = cc ^ (row&7) with matching read swizzle.
// All accesses CACHED (round-6 lesson: sc1-everywhere caps effective BW at ~430 GB/s).
template<int WMW, int WNW, int DEPTH, class Epi>
__device__ __forceinline__ void gemm_core(
    const short* __restrict__ A, const short* __restrict__ Bm,
    int K, int lda, int ldb, int bm0, int bn0, short* lds, Epi epi)
{
  constexpr int BK = 64, CPR = 8;                    // 16B chunks per row
  constexpr int BMR = WMW*64, BNR = WNW*64, T = WMW*WNW*64;
  constexpr int ACH = BMR*CPR, BCH = BNR*CPR;
  constexpr int BUF = (BMR+BNR)*BK;                  // shorts per buffer
  constexpr int LPS = (ACH+BCH)/T;                   // loads per thread per stage
  const int tid = threadIdx.x, lane = tid & 63, w = tid >> 6;
  const int wm = w / WNW, wn = w % WNW, lrow = lane & 15, lk8 = lane >> 4;

  f32x4 acc[4][4];
  #pragma unroll
  for (int i=0;i<4;++i)
    #pragma unroll
    for (int j=0;j<4;++j) acc[i][j] = (f32x4){0.f,0.f,0.f,0.f};

  auto stage = [&](int s){
    short* la = lds + (s & (DEPTH-1))*BUF;
    short* lb = la + BMR*BK;
    const int k0 = s*BK;
    #pragma unroll
    for (int i=tid; i<ACH; i+=T){
      int row = i>>3, sc = (i&7) ^ (row&7);
      const short* src = A + (size_t)(bm0+row)*lda + k0 + (sc<<3);
      __builtin_amdgcn_global_load_lds(
        (const __attribute__((address_space(1))) void*)src,
        (__attribute__((address_space(3))) void*)(la + i*8), 16, 0, 0);
    }
    #pragma unroll
    for (int i=tid; i<BCH; i+=T){
      int row = i>>3, sc = (i&7) ^ (row&7);
      const short* src = Bm + (size_t)(bn0+row)*ldb + k0 + (sc<<3);
      __builtin_amdgcn_global_load_lds(
        (const __attribute__((address_space(1))) void*)src,
        (__attribute__((address_space(3))) void*)(lb + i*8), 16, 0, 0);
    }
  };

  const int nk = K >> 6;
  for (int s=0; s<DEPTH-1 && s<nk; ++s) stage(s);
  for (int ks=0; ks<nk; ++ks){
    int C = nk - ks; if (C > DEPTH-1) C = DEPTH-1;   // stages in flight
    wait_vm<LPS>(C-1);                               // stage ks landed (this wave)
    __builtin_amdgcn_s_barrier();                    // all waves' stage ks landed
    __builtin_amdgcn_sched_barrier(0);
    if (ks + DEPTH-1 < nk) stage(ks + DEPTH-1);      // refill pipeline
    short* la = lds + (ks & (DEPTH-1))*BUF;
    short* lb = la + BMR*BK;
    #pragma unroll
    for (int kk=0; kk<2; ++kk){
      bf16x8 af[4], bfr[4];
      #pragma unroll
      for (int mi=0;mi<4;++mi){
        int row = wm*64 + mi*16 + lrow;
        int ch = row*8 + ((kk*4+lk8) ^ (row&7));
        af[mi] = *(const bf16x8*)(la + ch*8);
      }
      #pragma unroll
      for (int ni=0;ni<4;++ni){
        int row = wn*64 + ni*16 + lrow;
        int ch = row*8 + ((kk*4+lk8) ^ (row&7));
        bfr[ni] = *(const bf16x8*)(lb + ch*8);
      }
      #pragma unroll
      for (int mi=0;mi<4;++mi)
        #pragma unroll
        for (int ni=0;ni<4;++ni)
          acc[mi][ni] = __builtin_amdgcn_mfma_f32_16x16x32_bf16(af[mi], bfr[ni], acc[mi][ni], 0,0,0);
    }
  }
  // quad epilogue: rows r0..r0+3 (M-dir), fixed col
  #pragma unroll
  for (int mi=0;mi<4;++mi)
    #pragma unroll
    for (int ni=0;ni<4;++ni)
      epi(bm0 + wm*64 + mi*16 + lk8*4, bn0 + wn*64 + ni*16 + lrow, acc[mi][ni]);
}

// ---------------- epilogue functors (quad: rows r0..r0+3, col c) ----------------
struct EpiOut { float* C;
  __device__ void operator()(int r0,int c,f32x4 q) const {
    #pragma unroll
    for (int j=0;j<4;++j) C[(size_t)(r0+j)*D_+c]=q[j]; } };

struct EpiStoreBf { short* C;
  __device__ void operator()(int r0,int c,f32x4 q) const {
    #pragma unroll
    for (int j=0;j<4;++j) C[(size_t)(r0+j)*D_+c]=f2b(q[j]); } };

struct EpiBiasSig { float* C; const float* bias;
  __device__ void operator()(int r0,int c,f32x4 q) const {
    #pragma unroll
    for (int j=0;j<4;++j) C[(size_t)(r0+j)*D_+c] = sigf(q[j] + bias[c]); } };

struct EpiScat { short* dst; int part;   // -1: v[N,256,D]; 0: q rows; 1: k rows of qk[N,512,D]
  __device__ void operator()(int r0,int c,f32x4 q) const {
    #pragma unroll
    for (int j=0;j<4;++j){
      int r = r0+j;
      int b = r >> 11, s = r & 2047, t = s >> 6, ch = s & 63;
      short sv = f2b(siluf(q[j]));
      if (part < 0) dst[((size_t)t*256 +             b*64 + ch)*D_ + c] = sv;
      else          dst[((size_t)t*512 + part*256 + b*64 + ch)*D_ + c] = sv;
    } } };

template<int WMW, int WNW, class Epi>
__global__ __launch_bounds__(WMW*WNW*64)
void mgemm(const short* __restrict__ A, const short* __restrict__ Bm,
           int K, int lda, int ldb, Epi epi){
  __shared__ __align__(16) short lds[2*(WMW+WNW)*64*64];   // DEPTH=2, BK=64
  gemm_core<WMW,WNW,2>(A, Bm, K, lda, ldb, blockIdx.y*WMW*64, blockIdx.x*WNW*64, lds, epi);
}

// ---------------- grid barrier: leader-only release/acquire (G16-correct, cheap) -------------
// By __syncthreads, every wave's stores are complete in this CU's XCD L2. Leader then does ONE
// agent release fence (waitcnt + wbl2 -> dirty lines reach the coherence point), relaxed arrive,
// RELAXED spin (no per-poll cache ops -- round-4 lesson), and ONE agent acquire fence (inv of
// this CU's L1 + XCD L2) before __syncthreads lets the block read. 80 wbl2 + 80 inv per phase
// total, vs per-thread/per-poll maintenance (round 4) or no caching at all (rounds 5-6).
__device__ __forceinline__ void gsync(int* cnt, int target){
  asm volatile("s_waitcnt vmcnt(0) lgkmcnt(0)" ::: "memory");
  __syncthreads();
  if (threadIdx.x == 0){
    __builtin_amdgcn_fence(__ATOMIC_RELEASE, "agent");
    __hip_atomic_fetch_add(cnt, 1, __ATOMIC_RELAXED, __HIP_MEMORY_SCOPE_AGENT);
    while (__hip_atomic_load(cnt, __ATOMIC_RELAXED, __HIP_MEMORY_SCOPE_AGENT) < target)
      __builtin_amdgcn_s_sleep(4);
    __builtin_amdgcn_fence(__ATOMIC_ACQUIRE, "agent");
  }
  __syncthreads();
}

// ---------------- persistent scan kernel ----------------
__global__ __launch_bounds__(256)
void scan_coop(const short* __restrict__ qk, const short* __restrict__ vbuf,
               const short* __restrict__ ktT, const float* __restrict__ gates,
               short* __restrict__ preout, short* __restrict__ sgT,
               short* __restrict__ abuf, short* __restrict__ akT,
               short* __restrict__ dpred, short* __restrict__ dpredT, short* __restrict__ dh1T,
               float* __restrict__ W0c, float* __restrict__ W1c,
               float* __restrict__ S0m, float* __restrict__ S1m,
               short* __restrict__ W0b, short* __restrict__ W1b,
               short* __restrict__ W1bT0, short* __restrict__ W1bT1,
               int* __restrict__ bar)
{
  __shared__ __align__(16) short lds[4*(2+2)*64*64];   // DEPTH=4, 128 KB
  const int bid = blockIdx.x;
  int* cnt = bar;
  int ep = 0;

  for (int t=0; t<N_; ++t){
    const short* qkt = qk + (size_t)t*512*D_;
    const float al = gates[t], th = gates[N_+t], et = gates[2*N_+t];
    short* W1Tcur = (t&1) ? W1bT1 : W1bT0;
    short* W1Tnxt = (t&1) ? W1bT0 : W1bT1;

    // P1: h = [q;k] @ W0^T  -> abuf = silu(h); k rows also -> akT, sgT (transposed)
    if (bid < 32){
      int bm0=(bid>>3)*128, bn0=(bid&7)*128;
      gemm_core<2,2,4>(qkt, W0b, 1024, 1024, 1024, bm0, bn0, lds,
        [&](int r0,int c,f32x4 q){
          bf16x4 a4, g4;
          #pragma unroll
          for (int j=0;j<4;++j){
            a4[j] = f2b(siluf(q[j]));
            g4[j] = f2b(silugrad(q[j]));
            abuf[(size_t)(r0+j)*D_+c] = a4[j];
          }
          if (r0 >= 256){ int rr = r0-256;
            *(bf16x4*)&akT[(size_t)c*256+rr] = a4;
            *(bf16x4*)&sgT[(size_t)c*256+rr] = g4; }
        });
    }
    gsync(cnt, (++ep)*GRID_);

    // P2: pred = a @ W1^T -> retrieve (q rows) + dpred/dpredT (k rows)
    if (bid < 32){
      int bm0=(bid>>3)*128, bn0=(bid&7)*128;
      const short* vt = vbuf + (size_t)t*256*D_;
      gemm_core<2,2,4>(abuf, W1b, 1024, 1024, 1024, bm0, bn0, lds,
        [&](int r0,int c,f32x4 q){
          if (r0 < 256){
            #pragma unroll
            for (int j=0;j<4;++j){ int r=r0+j, b=r>>6, ch=r&63;
              preout[((size_t)b*S_ + t*CH_ + ch)*D_ + c] = f2b(q[j]); }
          } else { int rr = r0-256;
            bf16x4 d4;
            #pragma unroll
            for (int j=0;j<4;++j){
              float dv = C2_*(q[j] - b2f(vt[(size_t)(rr+j)*D_+c]));
              d4[j] = f2b(dv);
              dpred[(size_t)(rr+j)*D_+c] = d4[j];
            }
            *(bf16x4*)&dpredT[(size_t)c*256+rr] = d4; }
        });
    }
    gsync(cnt, (++ep)*GRID_);
    if (t == N_-1) break;   // last step: retrieval only

    // P3a (bid<16): dh1T[h,r] = (sum_o W1T[h,o] dpred[r,o]) * sgT[h,r]
    // P3b (16<=bid<80): g1T[h,o] = sum_r akT[h,r] dpredT[o,r]; fused W1 update
    if (bid < 16){
      int bm0=(bid>>1)*128, bn0=(bid&1)*128;
      gemm_core<2,2,4>(W1Tcur, dpred, 1024, 1024, 1024, bm0, bn0, lds,
        [&](int r0,int c,f32x4 q){
          #pragma unroll
          for (int j=0;j<4;++j){
            size_t i=(size_t)(r0+j)*256+c;
            dh1T[i] = f2b(q[j] * b2f(sgT[i]));
          }
        });
    } else if (bid < 80){
      int qd=bid-16, bm0=(qd>>3)*128, bn0=(qd&7)*128;   // rows=h, cols=o
      gemm_core<2,2,4>(akT, dpredT, 256, 256, 256, bm0, bn0, lds,
        [&](int r0,int c,f32x4 q){
          size_t mi = (size_t)c*D_ + r0;                 // masters W1[o,h]: h-quad contiguous
          f32x4 s4 = *(f32x4*)&S1m[mi];
          f32x4 w4 = *(f32x4*)&W1c[mi];
          bf16x4 nb;
          #pragma unroll
          for (int j=0;j<4;++j){
            float s = et*s4[j] - th*q[j];
            s4[j] = s;
            float wv = (1.f-al)*w4[j] + s;
            w4[j] = wv; nb[j] = f2b(wv);
          }
          *(f32x4*)&S1m[mi] = s4; *(f32x4*)&W1c[mi] = w4;
          *(bf16x4*)&W1b[mi] = nb;
          #pragma unroll
          for (int j=0;j<4;++j) W1Tnxt[(size_t)(r0+j)*D_ + c] = nb[j];
        });
    }
    gsync(cnt, (++ep)*GRID_);

    // P4: g0T[i,h] = sum_r ktT[i,r] dh1T[h,r]; fused W0 update (rows=i, cols=h)
    if (bid < 64){
      int bm0=(bid>>3)*128, bn0=(bid&7)*128;
      gemm_core<2,2,4>(ktT + (size_t)t*D_*256, dh1T, 256, 256, 256, bm0, bn0, lds,
        [&](int r0,int c,f32x4 q){
          size_t mi = (size_t)c*D_ + r0;                 // masters W0[h,i]: i-quad contiguous
          f32x4 s4 = *(f32x4*)&S0m[mi];
          f32x4 w4 = *(f32x4*)&W0c[mi];
          bf16x4 nb;
          #pragma unroll
          for (int j=0;j<4;++j){
            float s = et*s4[j] - th*q[j];
            s4[j] = s;
            float wv = (1.f-al)*w4[j] + s;
            w4[j] = wv; nb[j] = f2b(wv);
          }
          *(f32x4*)&S0m[mi] = s4; *(f32x4*)&W0c[mi] = w4;
          *(bf16x4*)&W0b[mi] = nb;
        });
    }
    gsync(cnt, (++ep)*GRID_);
  }
}

// ---------------- small kernels ----------------
__device__ __forceinline__ float block_sum(float v){
  #pragma unroll
  for (int o=32;o>0;o>>=1) v += __shfl_down(v,o,64);
  __shared__ float sm4[4];
  int lane = threadIdx.x & 63, w = threadIdx.x >> 6;
  if (lane==0) sm4[w]=v;
  __syncthreads();
  float r = sm4[0]+sm4[1]+sm4[2]+sm4[3];
  __syncthreads();
  return r;
}

__global__ void conv_k(const float* __restrict__ s, short* __restrict__ d, int n4){
  int i = blockIdx.x*256 + threadIdx.x;
  if (i >= n4) return;
  float4 v = ((const float4*)s)[i];
  bf16x4 o = { f2b(v.x), f2b(v.y), f2b(v.z), f2b(v.w) };
  ((bf16x4*)d)[i] = o;
}

__global__ __launch_bounds__(256)
void transpose_bf_k(const short* __restrict__ in, short* __restrict__ out,
                    int R, int C, size_t ibs, size_t obs){
  __shared__ short t[64][68];
  const short* ip = in + blockIdx.z*ibs;
  short* op = out + blockIdx.z*obs;
  int r0 = blockIdx.y*64, c0 = blockIdx.x*64;
  for (int i=threadIdx.x; i<1024; i+=256){
    int r = i>>4, c4 = (i&15)*4;
    *(bf16x4*)&t[r][c4] = *(const bf16x4*)&ip[(size_t)(r0+r)*C + c0+c4];
  }
  __syncthreads();
  for (int i=threadIdx.x; i<1024; i+=256){
    int c = i>>4, r4 = (i&15)*4;
    bf16x4 v = { t[r4+0][c], t[r4+1][c], t[r4+2][c], t[r4+3][c] };
    *(bf16x4*)&op[(size_t)(c0+c)*R + r0+r4] = v;
  }
}

__global__ __launch_bounds__(256)
void transpose_f2b_k(const float* __restrict__ in, short* __restrict__ out,
                     int R, int C, size_t ibs, size_t obs){
  __shared__ short t[64][68];
  const float* ip = in + blockIdx.z*ibs;
  short* op = out + blockIdx.z*obs;
  int r0 = blockIdx.y*64, c0 = blockIdx.x*64;
  for (int i=threadIdx.x; i<1024; i+=256){
    int r = i>>4, c4 = (i&15)*4;
    float4 v = *(const float4*)&ip[(size_t)(r0+r)*C + c0+c4];
    t[r][c4+0]=f2b(v.x); t[r][c4+1]=f2b(v.y); t[r][c4+2]=f2b(v.z); t[r][c4+3]=f2b(v.w);
  }
  __syncthreads();
  for (int i=threadIdx.x; i<1024; i+=256){
    int c = i>>4, r4 = (i&15)*4;
    bf16x4 v = { t[r4+0][c], t[r4+1][c], t[r4+2][c], t[r4+3][c] };
    *(bf16x4*)&op[(size_t)(c0+c)*R + r0+r4] = v;
  }
}

__global__ void chunk_mean_k(const float* __restrict__ x, short* __restrict__ cm){
  int idx = blockIdx.x*256 + threadIdx.x;     // B*N*D = 131072
  int d  = idx & (D_-1);
  int bn = idx >> 10;
  int b = bn >> 5, n = bn & 31;
  const float* p = x + ((size_t)b*S_ + n*CH_)*D_ + d;
  float s = 0.f;
  for (int ch=0; ch<CH_; ++ch) s += p[(size_t)ch*D_];
  cm[idx] = f2b(s * (1.f/CH_));
}

__global__ void gate_reduce_k(const float* __restrict__ Z, float* __restrict__ outp, float scale){
  int n = blockIdx.x;
  float s = 0.f;
  for (int b=0;b<B_;++b){
    const float* row = Z + (size_t)(b*N_+n)*D_;
    for (int j=threadIdx.x; j<D_; j+=256) s += row[j];
  }
  float tot = block_sum(s);
  if (threadIdx.x==0) outp[n] = scale * tot / (float)(B_*D_);
}

__global__ void rmsnorm2_k(const float* __restrict__ x, const float* __restrict__ gs,
                           const float* __restrict__ gr, short* __restrict__ xs, short* __restrict__ xr){
  size_t row = blockIdx.x;
  const float* xp = x + row*D_;
  float s = 0.f;
  for (int j=threadIdx.x;j<D_;j+=256){ float v=xp[j]; s+=v*v; }
  float tot = block_sum(s);
  float rinv = rsqrtf(tot/(float)D_ + EPS_);
  for (int j=threadIdx.x;j<D_;j+=256){
    float v = xp[j]*rinv;
    xs[row*D_+j] = f2b(v*gs[j]);
    xr[row*D_+j] = f2b(v*gr[j]);
  }
}

__global__ void l2norm_b(short* __restrict__ qk){
  size_t row = blockIdx.x;
  short* p = qk + row*D_;
  float s = 0.f;
  for (int j=threadIdx.x;j<D_;j+=256){ float v=b2f(p[j]); s+=v*v; }
  float tot = block_sum(s);
  float inv = 1.f / fmaxf(sqrtf(tot), 1e-12f);
  for (int j=threadIdx.x;j<D_;j+=256) p[j] = f2b(b2f(p[j])*inv);
}

__global__ void init_state_k(const float* __restrict__ W0, const float* __restrict__ W1,
                             float* __restrict__ W0c, float* __restrict__ W1c,
                             float* __restrict__ S0, float* __restrict__ S1,
                             short* __restrict__ W0b, short* __restrict__ W1b,
                             int* __restrict__ bar){
  size_t i = (size_t)blockIdx.x*256 + threadIdx.x;
  float a0=W0[i], a1=W1[i];
  W0c[i]=a0; W1c[i]=a1; S0[i]=0.f; S1[i]=0.f;
  W0b[i]=f2b(a0); W1b[i]=f2b(a1);
  if (i==0){ bar[0]=0; bar[1]=0; }
}

// ---------------- host ----------------
extern "C" void kernel_launch(void* const* d_in, const int* in_sizes, int n_in,
                              void* d_out, int out_size, void* d_ws, size_t ws_size,
                              hipStream_t stream) {
  (void)in_sizes; (void)n_in; (void)out_size;
  const float* x    = (const float*)d_in[0];
  const float* Mmet = (const float*)d_in[1];
  const float* Wk   = (const float*)d_in[2];
  const float* Wv   = (const float*)d_in[3];
  const float* Wq   = (const float*)d_in[4];
  const float* Wo   = (const float*)d_in[5];
  const float* Wgd  = (const float*)d_in[6];
  const float* bgd  = (const float*)d_in[7];
  const float* Wgl  = (const float*)d_in[8];
  const float* bgl  = (const float*)d_in[9];
  const float* Wgm  = (const float*)d_in[10];
  const float* bgm  = (const float*)d_in[11];
  const float* g_store = (const float*)d_in[12];
  const float* g_retr  = (const float*)d_in[13];
  const float* W0   = (const float*)d_in[14];
  const float* W1   = (const float*)d_in[15];
  float* out = (float*)d_out;

  if (ws_size < 160000000ull) return;   // layout below ~= 153.5 MB
  short* qk    = (short*)d_ws;          // [N,512,D] q rows 0..255, k rows 256..511
  short* vbuf  = qk    + 16777216;      // [N,256,D]
  short* xs    = vbuf  + 8388608;       // [B*S,D]
  short* xr    = xs    + 8388608;       // [B*S,D]  -> reused as ktT [N,1024,256]
  short* t1    = xr    + 8388608;       // [B*S,D]  -> reused as preout
  short* cm    = t1    + 8388608;       // [128,D]
  short* Wkb   = cm    + 131072;
  short* Wvb   = Wkb   + 1048576;
  short* Wqb   = Wvb   + 1048576;
  short* Wob   = Wqb   + 1048576;
  short* Wgdb  = Wob   + 1048576;
  short* Wglb  = Wgdb  + 1048576;
  short* Wgmb  = Wglb  + 1048576;
  short* MmetT = Wgmb  + 1048576;       // [B,D,D] transposed (bf16)
  short* W0b   = MmetT + 4194304;
  short* W1b   = W0b   + 1048576;
  short* W1bT0 = W1b   + 1048576;
  short* W1bT1 = W1bT0 + 1048576;
  short* abuf  = W1bT1 + 1048576;       // [512,D]
  short* akT   = abuf  + 524288;        // [D,256]
  short* sgT   = akT   + 262144;        // [D,256] silu'(h_k) bf16
  short* dpred = sgT   + 262144;        // [256,D]
  short* dpredT= dpred + 262144;        // [D,256]
  short* dh1T  = dpredT+ 262144;        // [D,256]
  float* Zg    = (float*)(dh1T + 262144);  // [128,D]
  float* gates = Zg    + 131072;        // [96]
  float* W0c   = gates + 128;
  float* W1c   = W0c   + 1048576;
  float* S0m   = W1c   + 1048576;
  float* S1m   = S0m   + 1048576;
  int*   bar   = (int*)(S1m + 1048576);
  short* ktT   = xr;                    // alias (xr dead before ktT written)
  short* preout= t1;                    // alias (t1 dead before scan)

  // conversions / init / static transposes
  conv_k<<<1024,256,0,stream>>>(Wk,  Wkb,  262144);
  conv_k<<<1024,256,0,stream>>>(Wv,  Wvb,  262144);
  conv_k<<<1024,256,0,stream>>>(Wq,  Wqb,  262144);
  conv_k<<<1024,256,0,stream>>>(Wo,  Wob,  262144);
  conv_k<<<1024,256,0,stream>>>(Wgd, Wgdb, 262144);
  conv_k<<<1024,256,0,stream>>>(Wgl, Wglb, 262144);
  conv_k<<<1024,256,0,stream>>>(Wgm, Wgmb, 262144);
  transpose_f2b_k<<<dim3(16,16,4),256,0,stream>>>(Mmet, MmetT, 1024, 1024, 1048576, 1048576);
  init_state_k<<<4096,256,0,stream>>>(W0, W1, W0c, W1c, S0m, S1m, W0b, W1b, bar);
  transpose_bf_k<<<dim3(16,16,1),256,0,stream>>>(W1b, W1bT0, 1024, 1024, 0, 0);

  // chunk means + gates
  chunk_mean_k<<<512,256,0,stream>>>(x, cm);
  {
    dim3 g(8,1);
    mgemm<2,2,EpiBiasSig><<<g,256,0,stream>>>(cm, Wgdb, 1024,1024,1024, EpiBiasSig{Zg, bgd});
    gate_reduce_k<<<N_,256,0,stream>>>(Zg, gates + 0,    0.01f);   // MEM_DECAY
    mgemm<2,2,EpiBiasSig><<<g,256,0,stream>>>(cm, Wglb, 1024,1024,1024, EpiBiasSig{Zg, bgl});
    gate_reduce_k<<<N_,256,0,stream>>>(Zg, gates + N_,   0.1f);    // MEM_LR
    mgemm<2,2,EpiBiasSig><<<g,256,0,stream>>>(cm, Wgmb, 1024,1024,1024, EpiBiasSig{Zg, bgm});
    gate_reduce_k<<<N_,256,0,stream>>>(Zg, gates + 2*N_, 0.9f);    // MEM_MOM
  }
  // dual RMSNorm
  rmsnorm2_k<<<B_*S_,256,0,stream>>>(x, g_store, g_retr, xs, xr);
  // t1 = xs @ Mmet[b]
  for (int b=0;b<B_;++b)
    mgemm<2,2,EpiStoreBf><<<dim3(8,16),256,0,stream>>>(
      xs + (size_t)b*S_*D_, MmetT + (size_t)b*D_*D_, 1024,1024,1024,
      EpiStoreBf{t1 + (size_t)b*S_*D_});
  // k, v, q projections with silu + chunk scatter
  {
    dim3 g(8,64);
    mgemm<2,2,EpiScat><<<g,256,0,stream>>>(t1, Wkb, 1024,1024,1024, EpiScat{qk, 1});
    mgemm<2,2,EpiScat><<<g,256,0,stream>>>(xs, Wvb, 1024,1024,1024, EpiScat{vbuf,-1});
    mgemm<2,2,EpiScat><<<g,256,0,stream>>>(xr, Wqb, 1024,1024,1024, EpiScat{qk, 0});
  }
  l2norm_b<<<N_*512,256,0,stream>>>(qk);
  // ktT[t][i][r] = qk[t][256+r][i]
  transpose_bf_k<<<dim3(16,4,32),256,0,stream>>>(qk + 256*1024, ktT, 256, 1024,
                                                 (size_t)512*1024, (size_t)1024*256);

  // persistent scan
  scan_coop<<<GRID_,256,0,stream>>>(qk, vbuf, ktT, gates, preout, sgT, abuf, akT,
                                    dpred, dpredT, dh1T, W0c, W1c, S0m, S1m,
                                    W0b, W1b, W1bT0, W1bT1, bar);

  // out = preout @ Wo^T
  mgemm<2,2,EpiOut><<<dim3(8,64),256,0,stream>>>(preout, Wob, 1024,1024,1024, EpiOut{out});
}